// Round 1
// baseline (972.635 us; speedup 1.0000x reference)
//
#include <hip/hip_runtime.h>
#include <math.h>

#define D_MODEL 512
#define NHEAD   8
#define DK      64
#define BATCH   4
#define SEQ     2048
#define MTOT    (BATCH*SEQ)

// ---------------------------------------------------------------------------
// Kernel 1: fused Q/K/V projection.  C = X @ W^T
//   X: (MTOT, 512) row-major.  W: (512, 512) row-major (output feature n = row n)
//   Output layout: (B, H, L, DK);  n-tile of 64 == exactly one head.
// grid: (MTOT/64, D_MODEL/64, 3), block: 256
// ---------------------------------------------------------------------------
__global__ __launch_bounds__(256) void qkv_gemm_kernel(
    const float* __restrict__ x,
    const float* __restrict__ Wq, const float* __restrict__ Wk,
    const float* __restrict__ Wv,
    float* __restrict__ Qo, float* __restrict__ Ko, float* __restrict__ Vo)
{
    const float* W   = (blockIdx.z == 0) ? Wq : (blockIdx.z == 1) ? Wk : Wv;
    float*       out = (blockIdx.z == 0) ? Qo : (blockIdx.z == 1) ? Ko : Vo;

    __shared__ float Xs[32][64];   // [k][m] transposed: reads broadcast/2-way
    __shared__ float Ws_[32][64];  // [k][n]

    const int t   = threadIdx.x;
    const int m0  = blockIdx.x * 64;
    const int h   = blockIdx.y;
    const int lm  = t & 63;
    const int kg  = t >> 6;            // 0..3 -> k cols kg*8 .. kg*8+7
    const int tc  = t & 15;
    const int tr  = t >> 4;
    const int tc4 = tc * 4, tr4 = tr * 4;

    float acc[4][4] = {};

    const float* xp = x + (size_t)(m0 + lm) * D_MODEL + kg * 8;
    const float* wp = W + (size_t)(h * DK + lm) * D_MODEL + kg * 8;

    for (int kt = 0; kt < D_MODEL; kt += 32) {
        float4 a0 = *(const float4*)(xp + kt);
        float4 a1 = *(const float4*)(xp + kt + 4);
        float4 b0 = *(const float4*)(wp + kt);
        float4 b1 = *(const float4*)(wp + kt + 4);
        __syncthreads();
        const int kb = kg * 8;
        Xs[kb+0][lm] = a0.x; Xs[kb+1][lm] = a0.y;
        Xs[kb+2][lm] = a0.z; Xs[kb+3][lm] = a0.w;
        Xs[kb+4][lm] = a1.x; Xs[kb+5][lm] = a1.y;
        Xs[kb+6][lm] = a1.z; Xs[kb+7][lm] = a1.w;
        Ws_[kb+0][lm] = b0.x; Ws_[kb+1][lm] = b0.y;
        Ws_[kb+2][lm] = b0.z; Ws_[kb+3][lm] = b0.w;
        Ws_[kb+4][lm] = b1.x; Ws_[kb+5][lm] = b1.y;
        Ws_[kb+6][lm] = b1.z; Ws_[kb+7][lm] = b1.w;
        __syncthreads();
        #pragma unroll
        for (int kk = 0; kk < 32; ++kk) {
            float4 a4 = *(const float4*)&Xs[kk][tr4];
            float4 b4 = *(const float4*)&Ws_[kk][tc4];
            float ai[4] = {a4.x, a4.y, a4.z, a4.w};
            float bj[4] = {b4.x, b4.y, b4.z, b4.w};
            #pragma unroll
            for (int i = 0; i < 4; ++i)
                #pragma unroll
                for (int j = 0; j < 4; ++j)
                    acc[i][j] = fmaf(ai[i], bj[j], acc[i][j]);
        }
    }

    #pragma unroll
    for (int i = 0; i < 4; ++i) {
        const int gm = m0 + tr4 + i;
        const int b  = gm >> 11;            // / SEQ
        const int l  = gm & (SEQ - 1);
        float4 v = make_float4(acc[i][0], acc[i][1], acc[i][2], acc[i][3]);
        *(float4*)(out + ((size_t)((b * NHEAD + h) * SEQ + l)) * DK + tc4) = v;
    }
}

// ---------------------------------------------------------------------------
// Kernel 2: flash-style attention with per-key-column wave modulation.
//   Q,K,V in (B,H,L,DK).  Output written as (B, L, H*DK) so the final GEMM
//   reads a plain (MTOT, 512) row-major matrix.
// grid: (SEQ/64, BATCH*NHEAD), block: 256
// ---------------------------------------------------------------------------
__global__ __launch_bounds__(256) void attn_kernel(
    const float* __restrict__ Q, const float* __restrict__ K,
    const float* __restrict__ V,
    const float* __restrict__ wave_freq, const float* __restrict__ wave_phase,
    float* __restrict__ Oout)
{
    const int bh = blockIdx.y;
    const int b  = bh / NHEAD;
    const int h  = bh % NHEAD;
    const int q0 = blockIdx.x * 64;

    __shared__ float Qs[64][64];   // [d][r]
    __shared__ float Ks[64][64];   // [d][c]
    __shared__ float Vs[64][68];   // [c][d]  (+4 pad: float4-aligned, 8-way max)
    __shared__ float Ps[64][68];   // [c][r]

    const int t   = threadIdx.x;
    const int lr  = t & 63;
    const int dg  = t >> 6;        // 0..3 -> 16-wide d group
    const int tc  = t & 15;
    const int tr  = t >> 4;
    const int tc4 = tc * 4, tr4 = tr * 4;

    const float freq  = wave_freq[h];
    const float phase = wave_phase[h];
    const float w2pf  = 6.28318530717958647692f * freq;
    const float scale = 0.125f;    // dk^-0.5

    const float* Qb = Q + (size_t)bh * SEQ * DK;
    const float* Kb = K + (size_t)bh * SEQ * DK;
    const float* Vb = V + (size_t)bh * SEQ * DK;

    // load Q tile transposed: Qs[d][r]
    {
        const float* qp = Qb + (size_t)(q0 + lr) * DK + dg * 16;
        #pragma unroll
        for (int i = 0; i < 4; ++i) {
            float4 v = *(const float4*)(qp + 4 * i);
            const int d = dg * 16 + 4 * i;
            Qs[d+0][lr] = v.x; Qs[d+1][lr] = v.y;
            Qs[d+2][lr] = v.z; Qs[d+3][lr] = v.w;
        }
    }

    float m_i[4], l_i[4], o[4][4];
    #pragma unroll
    for (int i = 0; i < 4; ++i) {
        m_i[i] = -INFINITY; l_i[i] = 0.f;
        #pragma unroll
        for (int j = 0; j < 4; ++j) o[i][j] = 0.f;
    }

    for (int ktile = 0; ktile < SEQ; ktile += 64) {
        // stage K (transposed) and V (natural, padded) tiles
        const float* kp = Kb + (size_t)(ktile + lr) * DK + dg * 16;
        const float* vp = Vb + (size_t)(ktile + lr) * DK + dg * 16;
        float4 kv[4], vv[4];
        #pragma unroll
        for (int i = 0; i < 4; ++i) {
            kv[i] = *(const float4*)(kp + 4 * i);
            vv[i] = *(const float4*)(vp + 4 * i);
        }
        __syncthreads();   // prev iter finished reading Ks/Vs/Ps (and Qs ready, iter 0)
        #pragma unroll
        for (int i = 0; i < 4; ++i) {
            const int d = dg * 16 + 4 * i;
            Ks[d+0][lr] = kv[i].x; Ks[d+1][lr] = kv[i].y;
            Ks[d+2][lr] = kv[i].z; Ks[d+3][lr] = kv[i].w;
            *(float4*)&Vs[lr][d] = vv[i];
        }
        __syncthreads();

        // S = Q K^T  (4x4 per thread: rows tr4+i, cols tc4+j)
        float s[4][4] = {};
        #pragma unroll 8
        for (int d = 0; d < 64; ++d) {
            float4 a4 = *(const float4*)&Qs[d][tr4];
            float4 b4 = *(const float4*)&Ks[d][tc4];
            float ai[4] = {a4.x, a4.y, a4.z, a4.w};
            float bj[4] = {b4.x, b4.y, b4.z, b4.w};
            #pragma unroll
            for (int i = 0; i < 4; ++i)
                #pragma unroll
                for (int j = 0; j < 4; ++j)
                    s[i][j] = fmaf(ai[i], bj[j], s[i][j]);
        }

        // scale + wave (per key column)
        float wv[4];
        #pragma unroll
        for (int j = 0; j < 4; ++j) {
            const float posf = (float)(ktile + tc4 + j);
            wv[j] = cosf(w2pf * posf + phase);
        }
        #pragma unroll
        for (int i = 0; i < 4; ++i)
            #pragma unroll
            for (int j = 0; j < 4; ++j)
                s[i][j] = s[i][j] * scale * wv[j];

        // row max across the 16 threads sharing each row
        float rm[4];
        #pragma unroll
        for (int i = 0; i < 4; ++i) {
            rm[i] = fmaxf(fmaxf(s[i][0], s[i][1]), fmaxf(s[i][2], s[i][3]));
        }
        #pragma unroll
        for (int mask = 1; mask <= 8; mask <<= 1)
            #pragma unroll
            for (int i = 0; i < 4; ++i)
                rm[i] = fmaxf(rm[i], __shfl_xor(rm[i], mask));

        // online softmax update (redundant but identical across the 16 threads)
        float p[4][4], rs[4], alpha[4];
        #pragma unroll
        for (int i = 0; i < 4; ++i) {
            const float m_new = fmaxf(m_i[i], rm[i]);
            alpha[i] = expf(m_i[i] - m_new);
            m_i[i] = m_new;
            rs[i] = 0.f;
            #pragma unroll
            for (int j = 0; j < 4; ++j) {
                p[i][j] = expf(s[i][j] - m_new);
                rs[i] += p[i][j];
            }
        }
        #pragma unroll
        for (int mask = 1; mask <= 8; mask <<= 1)
            #pragma unroll
            for (int i = 0; i < 4; ++i)
                rs[i] += __shfl_xor(rs[i], mask);
        #pragma unroll
        for (int i = 0; i < 4; ++i) {
            l_i[i] = l_i[i] * alpha[i] + rs[i];
            #pragma unroll
            for (int j = 0; j < 4; ++j) o[i][j] *= alpha[i];
        }

        // stage P transposed: Ps[c][r]
        #pragma unroll
        for (int i = 0; i < 4; ++i)
            #pragma unroll
            for (int j = 0; j < 4; ++j)
                Ps[tc4 + j][tr4 + i] = p[i][j];
        __syncthreads();

        // O += P @ V  (rows tr4+i, d-cols tc4+j)
        #pragma unroll 8
        for (int c = 0; c < 64; ++c) {
            float4 p4 = *(const float4*)&Ps[c][tr4];
            float4 v4 = *(const float4*)&Vs[c][tc4];
            float pi[4] = {p4.x, p4.y, p4.z, p4.w};
            float vj[4] = {v4.x, v4.y, v4.z, v4.w};
            #pragma unroll
            for (int i = 0; i < 4; ++i)
                #pragma unroll
                for (int j = 0; j < 4; ++j)
                    o[i][j] = fmaf(pi[i], vj[j], o[i][j]);
        }
    }

    // normalize + store to (B, L, H*DK)
    #pragma unroll
    for (int i = 0; i < 4; ++i) {
        const float inv = 1.0f / l_i[i];
        const int l = q0 + tr4 + i;
        float4 v = make_float4(o[i][0]*inv, o[i][1]*inv, o[i][2]*inv, o[i][3]*inv);
        *(float4*)(Oout + ((size_t)(b * SEQ + l)) * D_MODEL + h * DK + tc4) = v;
    }
}

// ---------------------------------------------------------------------------
// Kernel 3: output projection.  out = A @ Wo^T,  A: (MTOT, 512) row-major.
// grid: (MTOT/64, D_MODEL/64), block: 256
// ---------------------------------------------------------------------------
__global__ __launch_bounds__(256) void out_gemm_kernel(
    const float* __restrict__ A, const float* __restrict__ Wo,
    float* __restrict__ out)
{
    __shared__ float As[32][64];
    __shared__ float Ws_[32][64];

    const int t   = threadIdx.x;
    const int m0  = blockIdx.x * 64;
    const int n0  = blockIdx.y * 64;
    const int lm  = t & 63;
    const int kg  = t >> 6;
    const int tc  = t & 15;
    const int tr  = t >> 4;
    const int tc4 = tc * 4, tr4 = tr * 4;

    float acc[4][4] = {};

    const float* ap = A  + (size_t)(m0 + lm) * D_MODEL + kg * 8;
    const float* wp = Wo + (size_t)(n0 + lm) * D_MODEL + kg * 8;

    for (int kt = 0; kt < D_MODEL; kt += 32) {
        float4 a0 = *(const float4*)(ap + kt);
        float4 a1 = *(const float4*)(ap + kt + 4);
        float4 b0 = *(const float4*)(wp + kt);
        float4 b1 = *(const float4*)(wp + kt + 4);
        __syncthreads();
        const int kb = kg * 8;
        As[kb+0][lm] = a0.x; As[kb+1][lm] = a0.y;
        As[kb+2][lm] = a0.z; As[kb+3][lm] = a0.w;
        As[kb+4][lm] = a1.x; As[kb+5][lm] = a1.y;
        As[kb+6][lm] = a1.z; As[kb+7][lm] = a1.w;
        Ws_[kb+0][lm] = b0.x; Ws_[kb+1][lm] = b0.y;
        Ws_[kb+2][lm] = b0.z; Ws_[kb+3][lm] = b0.w;
        Ws_[kb+4][lm] = b1.x; Ws_[kb+5][lm] = b1.y;
        Ws_[kb+6][lm] = b1.z; Ws_[kb+7][lm] = b1.w;
        __syncthreads();
        #pragma unroll
        for (int kk = 0; kk < 32; ++kk) {
            float4 a4 = *(const float4*)&As[kk][tr4];
            float4 b4 = *(const float4*)&Ws_[kk][tc4];
            float ai[4] = {a4.x, a4.y, a4.z, a4.w};
            float bj[4] = {b4.x, b4.y, b4.z, b4.w};
            #pragma unroll
            for (int i = 0; i < 4; ++i)
                #pragma unroll
                for (int j = 0; j < 4; ++j)
                    acc[i][j] = fmaf(ai[i], bj[j], acc[i][j]);
        }
    }

    #pragma unroll
    for (int i = 0; i < 4; ++i) {
        const int gm = m0 + tr4 + i;
        float4 v = make_float4(acc[i][0], acc[i][1], acc[i][2], acc[i][3]);
        *(float4*)(out + (size_t)gm * D_MODEL + n0 + tc4) = v;
    }
}

// ---------------------------------------------------------------------------
extern "C" void kernel_launch(void* const* d_in, const int* in_sizes, int n_in,
                              void* d_out, int out_size, void* d_ws, size_t ws_size,
                              hipStream_t stream)
{
    (void)in_sizes; (void)n_in; (void)out_size; (void)ws_size;
    const float* x  = (const float*)d_in[0];
    const float* Wq = (const float*)d_in[1];
    const float* Wk = (const float*)d_in[2];
    const float* Wv = (const float*)d_in[3];
    const float* Wo = (const float*)d_in[4];
    const float* wf = (const float*)d_in[5];
    const float* wp = (const float*)d_in[6];
    float* out = (float*)d_out;

    const size_t QSZ = (size_t)BATCH * NHEAD * SEQ * DK;  // 4.19M floats
    float* Q  = (float*)d_ws;
    float* K  = Q + QSZ;
    float* V  = K + QSZ;
    float* AO = V + QSZ;   // attention output, (B, L, D) layout

    dim3 g1(MTOT / 64, D_MODEL / 64, 3);
    qkv_gemm_kernel<<<g1, 256, 0, stream>>>(x, Wq, Wk, Wv, Q, K, V);

    dim3 g2(SEQ / 64, BATCH * NHEAD);
    attn_kernel<<<g2, 256, 0, stream>>>(Q, K, V, wf, wp, AO);

    dim3 g3(MTOT / 64, D_MODEL / 64);
    out_gemm_kernel<<<g3, 256, 0, stream>>>(AO, Wo, out);
}

// Round 2
// 234.847 us; speedup vs baseline: 4.1416x; 4.1416x over previous
//
#include <hip/hip_runtime.h>
#include <math.h>

#define D_MODEL 512
#define NHEAD   8
#define DK      64
#define BATCH   4
#define SEQ     2048
#define MTOT    (BATCH*SEQ)

typedef _Float16 half8  __attribute__((ext_vector_type(8)));
typedef _Float16 half4_t __attribute__((ext_vector_type(4)));
typedef float    f32x4  __attribute__((ext_vector_type(4)));

#define MFMA16(a,b,c) __builtin_amdgcn_mfma_f32_16x16x32_f16((a),(b),(c),0,0,0)

// ---------------------------------------------------------------------------
// Kernel 0a: convert x and the 4 weight matrices to fp16.
// grid: 5120 x 256  (exactly (4.19M + 1.05M)/4 threads, 4 elems each)
// ---------------------------------------------------------------------------
__global__ __launch_bounds__(256) void cvt_kernel(
    const float* __restrict__ x,
    const float* __restrict__ Wq, const float* __restrict__ Wk,
    const float* __restrict__ Wv, const float* __restrict__ Wo,
    _Float16* __restrict__ Xh, _Float16* __restrict__ Wh)
{
    const int tid = blockIdx.x * 256 + threadIdx.x;
    int idx = tid * 4;
    const float* src; _Float16* dst; int off;
    if (idx < MTOT * D_MODEL) { src = x; dst = Xh; off = idx; }
    else {
        int r = idx - MTOT * D_MODEL;
        int sel = r >> 18;                 // 512*512 = 2^18
        off = r & ((1 << 18) - 1);
        src = (sel == 0) ? Wq : (sel == 1) ? Wk : (sel == 2) ? Wv : Wo;
        dst = Wh + ((size_t)sel << 18);
    }
    float4 v = *(const float4*)(src + off);
    half4_t h;
    h[0] = (_Float16)v.x; h[1] = (_Float16)v.y;
    h[2] = (_Float16)v.z; h[3] = (_Float16)v.w;
    *(half4_t*)(dst + off) = h;
}

// ---------------------------------------------------------------------------
// Kernel 0b: wave table  wtab[h][pos] = 0.125 * cos(2*pi*f_h*pos + phase_h)
// grid: 64 x 256
// ---------------------------------------------------------------------------
__global__ __launch_bounds__(256) void wave_kernel(
    const float* __restrict__ wf, const float* __restrict__ wp,
    float* __restrict__ wtab)
{
    const int i = blockIdx.x * 256 + threadIdx.x;   // 0 .. 16383
    const int h = i >> 11;
    const int pos = i & 2047;
    const float arg = fmaf(6.28318530717958647692f * wf[h], (float)pos, wp[h]);
    wtab[i] = 0.125f * cosf(arg);
}

// ---------------------------------------------------------------------------
// Kernel 1: fused QKV projection, fp16 MFMA.  C = Xh @ Wcat^T
//   tile 128(m) x 64(n); n-tile 64 == one head of one of {Q,K,V}.
//   Q,K out: (B,H,L,64) fp16.  V out: transposed (B,H,64,L) fp16.
// grid: (24, 64), block 256
// ---------------------------------------------------------------------------
__global__ __launch_bounds__(256) void qkv_mfma_kernel(
    const _Float16* __restrict__ Xh, const _Float16* __restrict__ Wh,
    _Float16* __restrict__ Qh, _Float16* __restrict__ Kh,
    _Float16* __restrict__ Vth)
{
    __shared__ _Float16 As[128][72];   // [m][k], pad 8
    __shared__ _Float16 Bs[64][72];    // [n][k]

    const int t  = threadIdx.x;
    const int n0 = blockIdx.x * 64;        // 0..1535
    const int m0 = blockIdx.y * 128;
    const int which = n0 >> 9;             // 0=Q 1=K 2=V
    const int h = (n0 >> 6) & 7;
    const _Float16* Wbase = Wh + ((size_t)which << 18) + (size_t)(h * 64) * 512;

    const int w = t >> 6, lane = t & 63, ln = lane & 15, quad = lane >> 4;
    const int ar = t >> 1, ac = (t & 1) * 32;   // A staging: row, col
    const int br = t >> 2, bc = (t & 3) * 16;   // B staging

    const _Float16* ag = Xh + (size_t)(m0 + ar) * 512 + ac;
    const _Float16* bg = Wbase + (size_t)br * 512 + bc;

    const f32x4 kZero = {0.f, 0.f, 0.f, 0.f};
    f32x4 acc[2][4];
    #pragma unroll
    for (int i = 0; i < 2; ++i)
        #pragma unroll
        for (int j = 0; j < 4; ++j) acc[i][j] = kZero;

    for (int k0 = 0; k0 < 512; k0 += 64) {
        half8 av[4], bv[2];
        #pragma unroll
        for (int i = 0; i < 4; ++i) av[i] = *(const half8*)(ag + k0 + i * 8);
        #pragma unroll
        for (int i = 0; i < 2; ++i) bv[i] = *(const half8*)(bg + k0 + i * 8);
        __syncthreads();
        #pragma unroll
        for (int i = 0; i < 4; ++i) *(half8*)&As[ar][ac + i * 8] = av[i];
        #pragma unroll
        for (int i = 0; i < 2; ++i) *(half8*)&Bs[br][bc + i * 8] = bv[i];
        __syncthreads();

        #pragma unroll
        for (int ks = 0; ks < 2; ++ks) {
            half8 af[2], bf[4];
            #pragma unroll
            for (int mt = 0; mt < 2; ++mt)
                af[mt] = *(const half8*)&As[w * 32 + mt * 16 + ln][ks * 32 + quad * 8];
            #pragma unroll
            for (int nt = 0; nt < 4; ++nt)
                bf[nt] = *(const half8*)&Bs[nt * 16 + ln][ks * 32 + quad * 8];
            #pragma unroll
            for (int mt = 0; mt < 2; ++mt)
                #pragma unroll
                for (int nt = 0; nt < 4; ++nt)
                    acc[mt][nt] = MFMA16(af[mt], bf[nt], acc[mt][nt]);
        }
    }

    const int b  = m0 >> 11;
    const int l0 = m0 & 2047;

    if (which < 2) {
        _Float16* dst = (which == 0 ? Qh : Kh) + (size_t)(b * NHEAD + h) * SEQ * DK;
        #pragma unroll
        for (int mt = 0; mt < 2; ++mt)
            #pragma unroll
            for (int nt = 0; nt < 4; ++nt)
                #pragma unroll
                for (int r = 0; r < 4; ++r) {
                    const int lq = l0 + w * 32 + mt * 16 + quad * 4 + r;
                    const int d  = nt * 16 + ln;
                    dst[(size_t)lq * DK + d] = (_Float16)acc[mt][nt][r];
                }
    } else {
        // transpose C-tile via LDS (reuse As: need 64 x 136 halves = 17.4KB <= 18.4KB)
        __syncthreads();
        _Float16* Vl = &As[0][0];
        #pragma unroll
        for (int mt = 0; mt < 2; ++mt)
            #pragma unroll
            for (int nt = 0; nt < 4; ++nt)
                #pragma unroll
                for (int r = 0; r < 4; ++r) {
                    const int lq = w * 32 + mt * 16 + quad * 4 + r;   // 0..127
                    const int d  = nt * 16 + ln;
                    Vl[d * 136 + lq] = (_Float16)acc[mt][nt][r];
                }
        __syncthreads();
        _Float16* dst = Vth + (size_t)(b * NHEAD + h) * DK * SEQ;
        const int d = t >> 2, c0 = (t & 3) * 32;
        #pragma unroll
        for (int i = 0; i < 4; ++i) {
            half8 v = *(const half8*)&Vl[d * 136 + c0 + i * 8];
            *(half8*)(dst + (size_t)d * SEQ + l0 + c0 + i * 8) = v;
        }
    }
}

// ---------------------------------------------------------------------------
// Kernel 2: flash attention, fp16 MFMA.
//   Q,K: (B,H,L,64) fp16;  Vt: (B,H,64,L) fp16;  out AO: (B,L,512) fp16.
// grid: (B*H, SEQ/64) — bh-major for XCD L2 locality of K/V. block 256.
// ---------------------------------------------------------------------------
__global__ __launch_bounds__(256) void attn_mfma_kernel(
    const _Float16* __restrict__ Qh, const _Float16* __restrict__ Kh,
    const _Float16* __restrict__ Vth, const float* __restrict__ wtab,
    _Float16* __restrict__ AOh)
{
    __shared__ _Float16 Qs[64][72];
    __shared__ _Float16 Ks[64][72];
    __shared__ _Float16 Vs[64][72];   // Vs[d][c] (V transposed)
    __shared__ _Float16 Ps[64][72];   // wave-private rows: wave w uses rows w*16..+15

    const int bh = blockIdx.x;
    const int q0 = blockIdx.y * 64;
    const int b = bh >> 3, h = bh & 7;

    const int t = threadIdx.x;
    const int w = t >> 6, lane = t & 63, ln = lane & 15, quad = lane >> 4;

    const _Float16* Qg = Qh + ((size_t)bh * SEQ + q0) * DK;
    const _Float16* Kg = Kh + (size_t)bh * SEQ * DK;
    const _Float16* Vg = Vth + (size_t)bh * DK * SEQ;
    const float* wt = wtab + h * SEQ;

    const int sr = t >> 2, sc = (t & 3) * 16;   // staging: row 0..63, col

    // stage Q tile once
    {
        half8 v0 = *(const half8*)(Qg + (size_t)sr * DK + sc);
        half8 v1 = *(const half8*)(Qg + (size_t)sr * DK + sc + 8);
        *(half8*)&Qs[sr][sc]     = v0;
        *(half8*)&Qs[sr][sc + 8] = v1;
    }
    __syncthreads();
    half8 qf[2];
    #pragma unroll
    for (int ks = 0; ks < 2; ++ks)
        qf[ks] = *(const half8*)&Qs[w * 16 + ln][ks * 32 + quad * 8];

    const f32x4 kZero = {0.f, 0.f, 0.f, 0.f};
    float m_i[4], l_i[4];
    f32x4 o[4];                      // o[nt][r]: row q=quad*4+r, col d=nt*16+ln
    #pragma unroll
    for (int r = 0; r < 4; ++r) { m_i[r] = -1e30f; l_i[r] = 0.f; }
    #pragma unroll
    for (int nt = 0; nt < 4; ++nt) o[nt] = kZero;

    for (int kt = 0; kt < SEQ; kt += 64) {
        half8 kv0 = *(const half8*)(Kg + (size_t)(kt + sr) * DK + sc);
        half8 kv1 = *(const half8*)(Kg + (size_t)(kt + sr) * DK + sc + 8);
        half8 vv0 = *(const half8*)(Vg + (size_t)sr * SEQ + kt + sc);
        half8 vv1 = *(const half8*)(Vg + (size_t)sr * SEQ + kt + sc + 8);
        float wv[4];
        #pragma unroll
        for (int nt = 0; nt < 4; ++nt) wv[nt] = wt[kt + nt * 16 + ln];
        __syncthreads();                       // prior frag reads of Ks/Vs done
        *(half8*)&Ks[sr][sc]     = kv0;
        *(half8*)&Ks[sr][sc + 8] = kv1;
        *(half8*)&Vs[sr][sc]     = vv0;
        *(half8*)&Vs[sr][sc + 8] = vv1;
        __syncthreads();

        // S = Q K^T  (wave's 16 q rows x 64 key cols)
        f32x4 s[4];
        #pragma unroll
        for (int nt = 0; nt < 4; ++nt) {
            half8 bf0 = *(const half8*)&Ks[nt * 16 + ln][quad * 8];
            half8 bf1 = *(const half8*)&Ks[nt * 16 + ln][32 + quad * 8];
            s[nt] = MFMA16(qf[0], bf0, kZero);
            s[nt] = MFMA16(qf[1], bf1, s[nt]);
        }

        // scale * wave (wtab already includes dk^-0.5)
        #pragma unroll
        for (int nt = 0; nt < 4; ++nt)
            #pragma unroll
            for (int r = 0; r < 4; ++r) s[nt][r] *= wv[nt];

        // row max over 64 cols: per-reg max over nt, then 16-lane shuffle tree
        float rm[4];
        #pragma unroll
        for (int r = 0; r < 4; ++r)
            rm[r] = fmaxf(fmaxf(s[0][r], s[1][r]), fmaxf(s[2][r], s[3][r]));
        #pragma unroll
        for (int mask = 1; mask <= 8; mask <<= 1)
            #pragma unroll
            for (int r = 0; r < 4; ++r)
                rm[r] = fmaxf(rm[r], __shfl_xor(rm[r], mask));

        float alpha[4], rs[4], p[4][4];
        #pragma unroll
        for (int r = 0; r < 4; ++r) {
            const float mn = fmaxf(m_i[r], rm[r]);
            alpha[r] = __expf(m_i[r] - mn);
            m_i[r] = mn;
            rs[r] = 0.f;
            #pragma unroll
            for (int nt = 0; nt < 4; ++nt) {
                p[nt][r] = __expf(s[nt][r] - mn);
                rs[r] += p[nt][r];
            }
        }
        #pragma unroll
        for (int mask = 1; mask <= 8; mask <<= 1)
            #pragma unroll
            for (int r = 0; r < 4; ++r)
                rs[r] += __shfl_xor(rs[r], mask);
        #pragma unroll
        for (int r = 0; r < 4; ++r) l_i[r] = l_i[r] * alpha[r] + rs[r];
        #pragma unroll
        for (int nt = 0; nt < 4; ++nt)
            #pragma unroll
            for (int r = 0; r < 4; ++r) o[nt][r] *= alpha[r];

        // P: C-layout -> A-layout via wave-private LDS rows (no block barrier)
        #pragma unroll
        for (int nt = 0; nt < 4; ++nt)
            #pragma unroll
            for (int r = 0; r < 4; ++r)
                Ps[w * 16 + quad * 4 + r][nt * 16 + ln] = (_Float16)p[nt][r];

        half8 pf[2];
        #pragma unroll
        for (int ks = 0; ks < 2; ++ks)
            pf[ks] = *(const half8*)&Ps[w * 16 + ln][ks * 32 + quad * 8];

        // O += P @ V   (B[n=d][k=c] from Vs rows)
        #pragma unroll
        for (int nt = 0; nt < 4; ++nt) {
            half8 vf0 = *(const half8*)&Vs[nt * 16 + ln][quad * 8];
            half8 vf1 = *(const half8*)&Vs[nt * 16 + ln][32 + quad * 8];
            o[nt] = MFMA16(pf[0], vf0, o[nt]);
            o[nt] = MFMA16(pf[1], vf1, o[nt]);
        }
    }

    // normalize + store AO (B, L, 512) fp16
    #pragma unroll
    for (int r = 0; r < 4; ++r) {
        const float inv = 1.f / l_i[r];
        const int lq = q0 + w * 16 + quad * 4 + r;
        const size_t base = ((size_t)b * SEQ + lq) * D_MODEL + h * DK;
        #pragma unroll
        for (int nt = 0; nt < 4; ++nt)
            AOh[base + nt * 16 + ln] = (_Float16)(o[nt][r] * inv);
    }
}

// ---------------------------------------------------------------------------
// Kernel 3: output projection, fp16 MFMA.  out = AOh @ Woh^T  (fp32 out)
// grid: (8, 64), block 256
// ---------------------------------------------------------------------------
__global__ __launch_bounds__(256) void out_mfma_kernel(
    const _Float16* __restrict__ AOh, const _Float16* __restrict__ Woh,
    float* __restrict__ out)
{
    __shared__ _Float16 As[128][72];
    __shared__ _Float16 Bs[64][72];

    const int t  = threadIdx.x;
    const int n0 = blockIdx.x * 64;
    const int m0 = blockIdx.y * 128;

    const int w = t >> 6, lane = t & 63, ln = lane & 15, quad = lane >> 4;
    const int ar = t >> 1, ac = (t & 1) * 32;
    const int br = t >> 2, bc = (t & 3) * 16;

    const _Float16* ag = AOh + (size_t)(m0 + ar) * 512 + ac;
    const _Float16* bg = Woh + (size_t)(n0 + br) * 512 + bc;

    const f32x4 kZero = {0.f, 0.f, 0.f, 0.f};
    f32x4 acc[2][4];
    #pragma unroll
    for (int i = 0; i < 2; ++i)
        #pragma unroll
        for (int j = 0; j < 4; ++j) acc[i][j] = kZero;

    for (int k0 = 0; k0 < 512; k0 += 64) {
        half8 av[4], bv[2];
        #pragma unroll
        for (int i = 0; i < 4; ++i) av[i] = *(const half8*)(ag + k0 + i * 8);
        #pragma unroll
        for (int i = 0; i < 2; ++i) bv[i] = *(const half8*)(bg + k0 + i * 8);
        __syncthreads();
        #pragma unroll
        for (int i = 0; i < 4; ++i) *(half8*)&As[ar][ac + i * 8] = av[i];
        #pragma unroll
        for (int i = 0; i < 2; ++i) *(half8*)&Bs[br][bc + i * 8] = bv[i];
        __syncthreads();

        #pragma unroll
        for (int ks = 0; ks < 2; ++ks) {
            half8 af[2], bf[4];
            #pragma unroll
            for (int mt = 0; mt < 2; ++mt)
                af[mt] = *(const half8*)&As[w * 32 + mt * 16 + ln][ks * 32 + quad * 8];
            #pragma unroll
            for (int nt = 0; nt < 4; ++nt)
                bf[nt] = *(const half8*)&Bs[nt * 16 + ln][ks * 32 + quad * 8];
            #pragma unroll
            for (int mt = 0; mt < 2; ++mt)
                #pragma unroll
                for (int nt = 0; nt < 4; ++nt)
                    acc[mt][nt] = MFMA16(af[mt], bf[nt], acc[mt][nt]);
        }
    }

    #pragma unroll
    for (int mt = 0; mt < 2; ++mt)
        #pragma unroll
        for (int nt = 0; nt < 4; ++nt)
            #pragma unroll
            for (int r = 0; r < 4; ++r) {
                const int gm = m0 + w * 32 + mt * 16 + quad * 4 + r;
                out[(size_t)gm * 512 + n0 + nt * 16 + ln] = acc[mt][nt][r];
            }
}

// ---------------------------------------------------------------------------
extern "C" void kernel_launch(void* const* d_in, const int* in_sizes, int n_in,
                              void* d_out, int out_size, void* d_ws, size_t ws_size,
                              hipStream_t stream)
{
    (void)in_sizes; (void)n_in; (void)out_size; (void)ws_size;
    const float* x  = (const float*)d_in[0];
    const float* Wq = (const float*)d_in[1];
    const float* Wk = (const float*)d_in[2];
    const float* Wv = (const float*)d_in[3];
    const float* Wo = (const float*)d_in[4];
    const float* wf = (const float*)d_in[5];
    const float* wp = (const float*)d_in[6];
    float* out = (float*)d_out;

    const size_t NX = (size_t)MTOT * D_MODEL;        // 4,194,304
    _Float16* Xh  = (_Float16*)d_ws;
    _Float16* Wh  = Xh + NX;                          // 4 x 262144
    _Float16* Qh  = Wh + 4 * 262144;
    _Float16* Kh  = Qh + NX;
    _Float16* Vth = Kh + NX;
    _Float16* AOh = Vth + NX;
    float*    wtab = (float*)(AOh + NX);              // 8 x 2048 fp32

    cvt_kernel<<<5120, 256, 0, stream>>>(x, Wq, Wk, Wv, Wo, Xh, Wh);
    wave_kernel<<<64, 256, 0, stream>>>(wf, wp, wtab);

    dim3 g1(24, 64);
    qkv_mfma_kernel<<<g1, 256, 0, stream>>>(Xh, Wh, Qh, Kh, Vth);

    dim3 g2(BATCH * NHEAD, SEQ / 64);
    attn_mfma_kernel<<<g2, 256, 0, stream>>>(Qh, Kh, Vth, wtab, AOh);

    dim3 g3(8, 64);
    out_mfma_kernel<<<g3, 256, 0, stream>>>(AOh, Wh + 3 * 262144, out);
}

// Round 4
// 178.403 us; speedup vs baseline: 5.4519x; 1.3164x over previous
//
#include <hip/hip_runtime.h>
#include <math.h>

#define D_MODEL 512
#define NHEAD   8
#define DK      64
#define BATCH   4
#define SEQ     2048
#define MTOT    (BATCH*SEQ)
#define NXELEM  (MTOT*D_MODEL)          // 4,194,304
#define NWELEM  (4*D_MODEL*D_MODEL)     // 1,048,576

typedef _Float16 half8   __attribute__((ext_vector_type(8)));
typedef _Float16 half4_t __attribute__((ext_vector_type(4)));
typedef float    f32x4   __attribute__((ext_vector_type(4)));

#define MFMA32(a,b,c) __builtin_amdgcn_mfma_f32_16x16x32_f16((a),(b),(c),0,0,0)

// ---------------------------------------------------------------------------
// Kernel 0: convert x + 4 weights to fp16, and build the wave table
//   wtab[h][pos] = 0.125 * cos(2*pi*f_h*pos + phase_h)   (0.125 = dk^-0.5)
// grid: 5136 x 256 (last 16 blocks do wtab)
// ---------------------------------------------------------------------------
__global__ __launch_bounds__(256) void cvt_kernel(
    const float* __restrict__ x,
    const float* __restrict__ Wq, const float* __restrict__ Wk,
    const float* __restrict__ Wv, const float* __restrict__ Wo,
    const float* __restrict__ wf, const float* __restrict__ wp,
    _Float16* __restrict__ Xh, _Float16* __restrict__ Wh,
    float* __restrict__ wtab)
{
    const int tid = blockIdx.x * 256 + threadIdx.x;
    int idx = tid * 4;
    if (idx < NXELEM + NWELEM) {
        const float* src; _Float16* dst; int off;
        if (idx < NXELEM) { src = x; dst = Xh; off = idx; }
        else {
            int r = idx - NXELEM;
            int sel = r >> 18;                 // 512*512 = 2^18
            off = r & ((1 << 18) - 1);
            src = (sel == 0) ? Wq : (sel == 1) ? Wk : (sel == 2) ? Wv : Wo;
            dst = Wh + ((size_t)sel << 18);
        }
        float4 v = *(const float4*)(src + off);
        half4_t h;
        h[0] = (_Float16)v.x; h[1] = (_Float16)v.y;
        h[2] = (_Float16)v.z; h[3] = (_Float16)v.w;
        *(half4_t*)(dst + off) = h;
    } else {
        int widx = idx - (NXELEM + NWELEM);    // 0 .. 16380, 4-aligned
        const int h = widx >> 11;
        const int pos0 = widx & 2047;
        const float f  = 6.28318530717958647692f * wf[h];
        const float ph = wp[h];
        float4 o;
        o.x = 0.125f * cosf(fmaf(f, (float)(pos0 + 0), ph));
        o.y = 0.125f * cosf(fmaf(f, (float)(pos0 + 1), ph));
        o.z = 0.125f * cosf(fmaf(f, (float)(pos0 + 2), ph));
        o.w = 0.125f * cosf(fmaf(f, (float)(pos0 + 3), ph));
        *(float4*)(wtab + widx) = o;
    }
}

// ---------------------------------------------------------------------------
// Kernel 1: fused QKV projection, fp16 MFMA.  C = Xh @ Wcat^T
//   Q out: (B,H,L,64) fp16 raw.
//   K out: (B,H,L,64) fp16, PRE-MULTIPLIED by wtab[h][pos] (scale+wave folded).
//   V out: transposed (B,H,64,L') fp16 where L' is swizzled per 32-key group:
//          key c = g*32 + kb16*16 + q*4 + r  ->  pos = g*32 + q*8 + kb16*4 + r
//          so a b128 read at [d][g*32+quad*8] is a K=32 PV B-fragment.
// grid: (24, 64), block 256
// ---------------------------------------------------------------------------
__global__ __launch_bounds__(256) void qkv_mfma_kernel(
    const _Float16* __restrict__ Xh, const _Float16* __restrict__ Wh,
    const float* __restrict__ wtab,
    _Float16* __restrict__ Qh, _Float16* __restrict__ Kh,
    _Float16* __restrict__ Vth)
{
    __shared__ _Float16 As[128][72];   // [m][k], pad 8
    __shared__ _Float16 Bs[64][72];    // [n][k]

    const int t  = threadIdx.x;
    const int n0 = blockIdx.x * 64;        // 0..1535
    const int m0 = blockIdx.y * 128;
    const int which = n0 >> 9;             // 0=Q 1=K 2=V
    const int h = (n0 >> 6) & 7;
    const _Float16* Wbase = Wh + ((size_t)which << 18) + (size_t)(h * 64) * 512;

    const int w = t >> 6, lane = t & 63, ln = lane & 15, quad = lane >> 4;
    const int ar = t >> 1, ac = (t & 1) * 32;   // A staging: row, col
    const int br = t >> 2, bc = (t & 3) * 16;   // B staging

    const _Float16* ag = Xh + (size_t)(m0 + ar) * 512 + ac;
    const _Float16* bg = Wbase + (size_t)br * 512 + bc;

    const f32x4 kZero = {0.f, 0.f, 0.f, 0.f};
    f32x4 acc[2][4];
    #pragma unroll
    for (int i = 0; i < 2; ++i)
        #pragma unroll
        for (int j = 0; j < 4; ++j) acc[i][j] = kZero;

    for (int k0 = 0; k0 < 512; k0 += 64) {
        half8 av[4], bv[2];
        #pragma unroll
        for (int i = 0; i < 4; ++i) av[i] = *(const half8*)(ag + k0 + i * 8);
        #pragma unroll
        for (int i = 0; i < 2; ++i) bv[i] = *(const half8*)(bg + k0 + i * 8);
        __syncthreads();
        #pragma unroll
        for (int i = 0; i < 4; ++i) *(half8*)&As[ar][ac + i * 8] = av[i];
        #pragma unroll
        for (int i = 0; i < 2; ++i) *(half8*)&Bs[br][bc + i * 8] = bv[i];
        __syncthreads();

        #pragma unroll
        for (int ks = 0; ks < 2; ++ks) {
            half8 af[2], bf[4];
            #pragma unroll
            for (int mt = 0; mt < 2; ++mt)
                af[mt] = *(const half8*)&As[w * 32 + mt * 16 + ln][ks * 32 + quad * 8];
            #pragma unroll
            for (int nt = 0; nt < 4; ++nt)
                bf[nt] = *(const half8*)&Bs[nt * 16 + ln][ks * 32 + quad * 8];
            #pragma unroll
            for (int mt = 0; mt < 2; ++mt)
                #pragma unroll
                for (int nt = 0; nt < 4; ++nt)
                    acc[mt][nt] = MFMA32(af[mt], bf[nt], acc[mt][nt]);
        }
    }

    const int b  = m0 >> 11;
    const int l0 = m0 & 2047;

    if (which < 2) {
        _Float16* dst = (which == 0 ? Qh : Kh) + (size_t)(b * NHEAD + h) * SEQ * DK;
        const float* wt = wtab + h * SEQ;
        #pragma unroll
        for (int mt = 0; mt < 2; ++mt)
            #pragma unroll
            for (int r = 0; r < 4; ++r) {
                const int lq = l0 + w * 32 + mt * 16 + quad * 4 + r;
                const float wv = (which == 1) ? wt[lq] : 1.0f;
                #pragma unroll
                for (int nt = 0; nt < 4; ++nt) {
                    const int d = nt * 16 + ln;
                    dst[(size_t)lq * DK + d] = (_Float16)(acc[mt][nt][r] * wv);
                }
            }
    } else {
        // transpose + swizzle C-tile via LDS (reuse As: 64 x 136 halves = 17.4KB)
        __syncthreads();
        _Float16* Vl = &As[0][0];
        #pragma unroll
        for (int mt = 0; mt < 2; ++mt)
            #pragma unroll
            for (int nt = 0; nt < 4; ++nt)
                #pragma unroll
                for (int r = 0; r < 4; ++r) {
                    const int lq = w * 32 + mt * 16 + quad * 4 + r;   // 0..127
                    const int k32 = lq & 31;
                    const int pos = (lq & ~31) | (((k32 >> 2) & 3) << 3)
                                  | ((k32 >> 4) << 2) | (k32 & 3);
                    const int d  = nt * 16 + ln;
                    Vl[d * 136 + pos] = (_Float16)acc[mt][nt][r];
                }
        __syncthreads();
        _Float16* dst = Vth + (size_t)(b * NHEAD + h) * DK * SEQ;
        const int d = t >> 2, c0 = (t & 3) * 32;
        #pragma unroll
        for (int i = 0; i < 4; ++i) {
            half8 v = *(const half8*)&Vl[d * 136 + c0 + i * 8];
            *(half8*)(dst + (size_t)d * SEQ + l0 + c0 + i * 8) = v;
        }
    }
}

// ---------------------------------------------------------------------------
// Kernel 2: flash attention, fp16 MFMA (16x16x32 only), max-free softmax.
//   S^T = MFMA(A=K'-frag, B=Q-frag): lane holds p for keys {quad*4+r} at
//   q=ln.  Over two adjacent 16-key tiles this is exactly a K=32 A-fragment
//   (k' = quad*8 + kb16*4 + r), matching the swizzled-V B-fragment.
//   K' already contains 0.125*wave.
// grid: (B*H, SEQ/64), block 256
// ---------------------------------------------------------------------------
__global__ __launch_bounds__(256) void attn_mfma_kernel(
    const _Float16* __restrict__ Qh, const _Float16* __restrict__ Kwh,
    const _Float16* __restrict__ Vth, _Float16* __restrict__ AOh)
{
    __shared__ _Float16 Qs[64][72];
    __shared__ _Float16 Ks[64][72];
    __shared__ _Float16 Vs[64][72];   // Vs[d][swizzled key]

    const int bh = blockIdx.x;
    const int q0 = blockIdx.y * 64;
    const int b = bh >> 3, h = bh & 7;

    const int t = threadIdx.x;
    const int w = t >> 6, lane = t & 63, ln = lane & 15, quad = lane >> 4;

    const _Float16* Qg = Qh + ((size_t)bh * SEQ + q0) * DK;
    const _Float16* Kg = Kwh + (size_t)bh * SEQ * DK;
    const _Float16* Vg = Vth + (size_t)bh * DK * SEQ;

    const int sr = t >> 2, sc = (t & 3) * 16;   // staging: row 0..63, col

    // stage Q tile once
    *(half8*)&Qs[sr][sc]     = *(const half8*)(Qg + (size_t)sr * DK + sc);
    *(half8*)&Qs[sr][sc + 8] = *(const half8*)(Qg + (size_t)sr * DK + sc + 8);
    __syncthreads();
    half8 qf0 = *(const half8*)&Qs[w * 16 + ln][quad * 8];
    half8 qf1 = *(const half8*)&Qs[w * 16 + ln][32 + quad * 8];

    const f32x4 kZero = {0.f, 0.f, 0.f, 0.f};
    f32x4 o[4];                      // o[nt][r]: q row quad*4+r, d col nt*16+ln
    #pragma unroll
    for (int nt = 0; nt < 4; ++nt) o[nt] = kZero;
    float l_acc = 0.f;               // per-lane partial denom for q row = w*16+ln

    for (int kt = 0; kt < SEQ; kt += 64) {
        half8 kv0 = *(const half8*)(Kg + (size_t)(kt + sr) * DK + sc);
        half8 kv1 = *(const half8*)(Kg + (size_t)(kt + sr) * DK + sc + 8);
        half8 vv0 = *(const half8*)(Vg + (size_t)sr * SEQ + kt + sc);
        half8 vv1 = *(const half8*)(Vg + (size_t)sr * SEQ + kt + sc + 8);
        __syncthreads();                       // prior frag reads done
        *(half8*)&Ks[sr][sc]     = kv0;
        *(half8*)&Ks[sr][sc + 8] = kv1;
        *(half8*)&Vs[sr][sc]     = vv0;
        *(half8*)&Vs[sr][sc + 8] = vv1;
        __syncthreads();

        #pragma unroll
        for (int g = 0; g < 2; ++g) {
            // S^T for 16-key blocks kb=2g, 2g+1
            half8 ka0 = *(const half8*)&Ks[(2*g+0) * 16 + ln][quad * 8];
            half8 ka1 = *(const half8*)&Ks[(2*g+0) * 16 + ln][32 + quad * 8];
            half8 kb0 = *(const half8*)&Ks[(2*g+1) * 16 + ln][quad * 8];
            half8 kb1 = *(const half8*)&Ks[(2*g+1) * 16 + ln][32 + quad * 8];
            f32x4 s0 = MFMA32(ka0, qf0, kZero);
            f32x4 s1 = MFMA32(kb0, qf0, kZero);
            s0 = MFMA32(ka1, qf1, s0);
            s1 = MFMA32(kb1, qf1, s1);

            // p = exp(s); build K=32 A-fragment: pf[j] = kb16*4+r ordering
            half8 pf;
            float ps = 0.f;
            #pragma unroll
            for (int r = 0; r < 4; ++r) {
                const float e0 = __expf(s0[r]);
                const float e1 = __expf(s1[r]);
                pf[r]     = (_Float16)e0;
                pf[r + 4] = (_Float16)e1;
                ps += e0 + e1;
            }
            l_acc += ps;

            // O += P @ V  over these 32 keys
            #pragma unroll
            for (int nt = 0; nt < 4; ++nt) {
                half8 vf = *(const half8*)&Vs[nt * 16 + ln][g * 32 + quad * 8];
                o[nt] = MFMA32(pf, vf, o[nt]);
            }
        }
    }

    // reduce denominator across quads (lanes ln, 16+ln, 32+ln, 48+ln)
    l_acc += __shfl_xor(l_acc, 16);
    l_acc += __shfl_xor(l_acc, 32);

    // normalize + store AO (B, L, 512) fp16
    #pragma unroll
    for (int r = 0; r < 4; ++r) {
        const float lr  = __shfl(l_acc, quad * 4 + r, 16);
        const float inv = 1.0f / lr;
        const int lq = q0 + w * 16 + quad * 4 + r;
        const size_t base = ((size_t)b * SEQ + lq) * D_MODEL + h * DK;
        #pragma unroll
        for (int nt = 0; nt < 4; ++nt)
            AOh[base + nt * 16 + ln] = (_Float16)(o[nt][r] * inv);
    }
}

// ---------------------------------------------------------------------------
// Kernel 3: output projection, fp16 MFMA.  out = AOh @ Woh^T  (fp32 out)
// grid: (8, 64), block 256
// ---------------------------------------------------------------------------
__global__ __launch_bounds__(256) void out_mfma_kernel(
    const _Float16* __restrict__ AOh, const _Float16* __restrict__ Woh,
    float* __restrict__ out)
{
    __shared__ _Float16 As[128][72];
    __shared__ _Float16 Bs[64][72];

    const int t  = threadIdx.x;
    const int n0 = blockIdx.x * 64;
    const int m0 = blockIdx.y * 128;

    const int w = t >> 6, lane = t & 63, ln = lane & 15, quad = lane >> 4;
    const int ar = t >> 1, ac = (t & 1) * 32;
    const int br = t >> 2, bc = (t & 3) * 16;

    const _Float16* ag = AOh + (size_t)(m0 + ar) * 512 + ac;
    const _Float16* bg = Woh + (size_t)(n0 + br) * 512 + bc;

    const f32x4 kZero = {0.f, 0.f, 0.f, 0.f};
    f32x4 acc[2][4];
    #pragma unroll
    for (int i = 0; i < 2; ++i)
        #pragma unroll
        for (int j = 0; j < 4; ++j) acc[i][j] = kZero;

    for (int k0 = 0; k0 < 512; k0 += 64) {
        half8 av[4], bv[2];
        #pragma unroll
        for (int i = 0; i < 4; ++i) av[i] = *(const half8*)(ag + k0 + i * 8);
        #pragma unroll
        for (int i = 0; i < 2; ++i) bv[i] = *(const half8*)(bg + k0 + i * 8);
        __syncthreads();
        #pragma unroll
        for (int i = 0; i < 4; ++i) *(half8*)&As[ar][ac + i * 8] = av[i];
        #pragma unroll
        for (int i = 0; i < 2; ++i) *(half8*)&Bs[br][bc + i * 8] = bv[i];
        __syncthreads();

        #pragma unroll
        for (int ks = 0; ks < 2; ++ks) {
            half8 af[2], bf[4];
            #pragma unroll
            for (int mt = 0; mt < 2; ++mt)
                af[mt] = *(const half8*)&As[w * 32 + mt * 16 + ln][ks * 32 + quad * 8];
            #pragma unroll
            for (int nt = 0; nt < 4; ++nt)
                bf[nt] = *(const half8*)&Bs[nt * 16 + ln][ks * 32 + quad * 8];
            #pragma unroll
            for (int mt = 0; mt < 2; ++mt)
                #pragma unroll
                for (int nt = 0; nt < 4; ++nt)
                    acc[mt][nt] = MFMA32(af[mt], bf[nt], acc[mt][nt]);
        }
    }

    #pragma unroll
    for (int mt = 0; mt < 2; ++mt)
        #pragma unroll
        for (int nt = 0; nt < 4; ++nt)
            #pragma unroll
            for (int r = 0; r < 4; ++r) {
                const int gm = m0 + w * 32 + mt * 16 + quad * 4 + r;
                out[(size_t)gm * 512 + n0 + nt * 16 + ln] = acc[mt][nt][r];
            }
}

// ---------------------------------------------------------------------------
extern "C" void kernel_launch(void* const* d_in, const int* in_sizes, int n_in,
                              void* d_out, int out_size, void* d_ws, size_t ws_size,
                              hipStream_t stream)
{
    (void)in_sizes; (void)n_in; (void)out_size; (void)ws_size;
    const float* x  = (const float*)d_in[0];
    const float* Wq = (const float*)d_in[1];
    const float* Wk = (const float*)d_in[2];
    const float* Wv = (const float*)d_in[3];
    const float* Wo = (const float*)d_in[4];
    const float* wf = (const float*)d_in[5];
    const float* wp = (const float*)d_in[6];
    float* out = (float*)d_out;

    const size_t NX = (size_t)MTOT * D_MODEL;        // 4,194,304
    _Float16* Xh  = (_Float16*)d_ws;
    _Float16* Wh  = Xh + NX;                          // 4 x 262144
    _Float16* Qh  = Wh + 4 * 262144;
    _Float16* Kh  = Qh + NX;                          // pre-scaled K'
    _Float16* Vth = Kh + NX;                          // transposed+swizzled V
    _Float16* AOh = Vth + NX;
    float*    wtab = (float*)(AOh + NX);              // 8 x 2048 fp32

    cvt_kernel<<<5136, 256, 0, stream>>>(x, Wq, Wk, Wv, Wo, wf, wp, Xh, Wh, wtab);

    dim3 g1(24, 64);
    qkv_mfma_kernel<<<g1, 256, 0, stream>>>(Xh, Wh, wtab, Qh, Kh, Vth);

    dim3 g2(BATCH * NHEAD, SEQ / 64);
    attn_mfma_kernel<<<g2, 256, 0, stream>>>(Qh, Kh, Vth, AOh);

    dim3 g3(8, 64);
    out_mfma_kernel<<<g3, 256, 0, stream>>>(AOh, Wh + 3 * 262144, out);
}

// Round 6
// 168.383 us; speedup vs baseline: 5.7763x; 1.0595x over previous
//
#include <hip/hip_runtime.h>
#include <math.h>

#define D_MODEL 512
#define NHEAD   8
#define DK      64
#define BATCH   4
#define SEQ     2048
#define MTOT    (BATCH*SEQ)
#define NXELEM  (MTOT*D_MODEL)          // 4,194,304
#define NWELEM  (4*D_MODEL*D_MODEL)     // 1,048,576

typedef _Float16 half8   __attribute__((ext_vector_type(8)));
typedef _Float16 half4_t __attribute__((ext_vector_type(4)));
typedef float    f32x4   __attribute__((ext_vector_type(4)));

#define MFMA32(a,b,c) __builtin_amdgcn_mfma_f32_16x16x32_f16((a),(b),(c),0,0,0)

// ---------------------------------------------------------------------------
// Kernel 0: convert x + 4 weights to fp16, and build the wave table
//   wtab[h][pos] = 0.125 * cos(2*pi*f_h*pos + phase_h)   (0.125 = dk^-0.5)
// grid: 5136 x 256 (last 16 blocks do wtab)
// ---------------------------------------------------------------------------
__global__ __launch_bounds__(256) void cvt_kernel(
    const float* __restrict__ x,
    const float* __restrict__ Wq, const float* __restrict__ Wk,
    const float* __restrict__ Wv, const float* __restrict__ Wo,
    const float* __restrict__ wf, const float* __restrict__ wp,
    _Float16* __restrict__ Xh, _Float16* __restrict__ Wh,
    float* __restrict__ wtab)
{
    const int tid = blockIdx.x * 256 + threadIdx.x;
    int idx = tid * 4;
    if (idx < NXELEM + NWELEM) {
        const float* src; _Float16* dst; int off;
        if (idx < NXELEM) { src = x; dst = Xh; off = idx; }
        else {
            int r = idx - NXELEM;
            int sel = r >> 18;                 // 512*512 = 2^18
            off = r & ((1 << 18) - 1);
            src = (sel == 0) ? Wq : (sel == 1) ? Wk : (sel == 2) ? Wv : Wo;
            dst = Wh + ((size_t)sel << 18);
        }
        float4 v = *(const float4*)(src + off);
        half4_t h;
        h[0] = (_Float16)v.x; h[1] = (_Float16)v.y;
        h[2] = (_Float16)v.z; h[3] = (_Float16)v.w;
        *(half4_t*)(dst + off) = h;
    } else {
        int widx = idx - (NXELEM + NWELEM);    // 0 .. 16380, 4-aligned
        const int h = widx >> 11;
        const int pos0 = widx & 2047;
        const float f  = 6.28318530717958647692f * wf[h];
        const float ph = wp[h];
        float4 o;
        o.x = 0.125f * cosf(fmaf(f, (float)(pos0 + 0), ph));
        o.y = 0.125f * cosf(fmaf(f, (float)(pos0 + 1), ph));
        o.z = 0.125f * cosf(fmaf(f, (float)(pos0 + 2), ph));
        o.w = 0.125f * cosf(fmaf(f, (float)(pos0 + 3), ph));
        *(float4*)(wtab + widx) = o;
    }
}

// ---------------------------------------------------------------------------
// Kernel 1: fused QKV projection, fp16 MFMA.  C = Xh @ Wcat^T
//   Q out: (B,H,L,64) fp16 raw.
//   K out: (B,H,L,64) fp16, PRE-MULTIPLIED by wtab[h][pos] (scale+wave folded).
//   V out: transposed (B,H,64,L') fp16 where L' is swizzled per 32-key group:
//          key c = g*32 + kb16*16 + q*4 + r  ->  pos = g*32 + q*8 + kb16*4 + r
//          so a b128 read at [d][g*32+quad*8] is a K=32 PV B-fragment.
// grid: (24, 64), block 256
// ---------------------------------------------------------------------------
__global__ __launch_bounds__(256) void qkv_mfma_kernel(
    const _Float16* __restrict__ Xh, const _Float16* __restrict__ Wh,
    const float* __restrict__ wtab,
    _Float16* __restrict__ Qh, _Float16* __restrict__ Kh,
    _Float16* __restrict__ Vth)
{
    __shared__ _Float16 As[128][72];   // [m][k], pad 8
    __shared__ _Float16 Bs[64][72];    // [n][k]

    const int t  = threadIdx.x;
    const int n0 = blockIdx.x * 64;        // 0..1535
    const int m0 = blockIdx.y * 128;
    const int which = n0 >> 9;             // 0=Q 1=K 2=V
    const int h = (n0 >> 6) & 7;
    const _Float16* Wbase = Wh + ((size_t)which << 18) + (size_t)(h * 64) * 512;

    const int w = t >> 6, lane = t & 63, ln = lane & 15, quad = lane >> 4;
    const int ar = t >> 1, ac = (t & 1) * 32;   // A staging: row, col
    const int br = t >> 2, bc = (t & 3) * 16;   // B staging

    const _Float16* ag = Xh + (size_t)(m0 + ar) * 512 + ac;
    const _Float16* bg = Wbase + (size_t)br * 512 + bc;

    const f32x4 kZero = {0.f, 0.f, 0.f, 0.f};
    f32x4 acc[2][4];
    #pragma unroll
    for (int i = 0; i < 2; ++i)
        #pragma unroll
        for (int j = 0; j < 4; ++j) acc[i][j] = kZero;

    for (int k0 = 0; k0 < 512; k0 += 64) {
        half8 av[4], bv[2];
        #pragma unroll
        for (int i = 0; i < 4; ++i) av[i] = *(const half8*)(ag + k0 + i * 8);
        #pragma unroll
        for (int i = 0; i < 2; ++i) bv[i] = *(const half8*)(bg + k0 + i * 8);
        __syncthreads();
        #pragma unroll
        for (int i = 0; i < 4; ++i) *(half8*)&As[ar][ac + i * 8] = av[i];
        #pragma unroll
        for (int i = 0; i < 2; ++i) *(half8*)&Bs[br][bc + i * 8] = bv[i];
        __syncthreads();

        #pragma unroll
        for (int ks = 0; ks < 2; ++ks) {
            half8 af[2], bf[4];
            #pragma unroll
            for (int mt = 0; mt < 2; ++mt)
                af[mt] = *(const half8*)&As[w * 32 + mt * 16 + ln][ks * 32 + quad * 8];
            #pragma unroll
            for (int nt = 0; nt < 4; ++nt)
                bf[nt] = *(const half8*)&Bs[nt * 16 + ln][ks * 32 + quad * 8];
            #pragma unroll
            for (int mt = 0; mt < 2; ++mt)
                #pragma unroll
                for (int nt = 0; nt < 4; ++nt)
                    acc[mt][nt] = MFMA32(af[mt], bf[nt], acc[mt][nt]);
        }
    }

    const int b  = m0 >> 11;
    const int l0 = m0 & 2047;

    if (which < 2) {
        _Float16* dst = (which == 0 ? Qh : Kh) + (size_t)(b * NHEAD + h) * SEQ * DK;
        const float* wt = wtab + h * SEQ;
        #pragma unroll
        for (int mt = 0; mt < 2; ++mt)
            #pragma unroll
            for (int r = 0; r < 4; ++r) {
                const int lq = l0 + w * 32 + mt * 16 + quad * 4 + r;
                const float wv = (which == 1) ? wt[lq] : 1.0f;
                #pragma unroll
                for (int nt = 0; nt < 4; ++nt) {
                    const int d = nt * 16 + ln;
                    dst[(size_t)lq * DK + d] = (_Float16)(acc[mt][nt][r] * wv);
                }
            }
    } else {
        // transpose + swizzle C-tile via LDS (reuse As: 64 x 136 halves = 17.4KB)
        __syncthreads();
        _Float16* Vl = &As[0][0];
        #pragma unroll
        for (int mt = 0; mt < 2; ++mt)
            #pragma unroll
            for (int nt = 0; nt < 4; ++nt)
                #pragma unroll
                for (int r = 0; r < 4; ++r) {
                    const int lq = w * 32 + mt * 16 + quad * 4 + r;   // 0..127
                    const int k32 = lq & 31;
                    const int pos = (lq & ~31) | (((k32 >> 2) & 3) << 3)
                                  | ((k32 >> 4) << 2) | (k32 & 3);
                    const int d  = nt * 16 + ln;
                    Vl[d * 136 + pos] = (_Float16)acc[mt][nt][r];
                }
        __syncthreads();
        _Float16* dst = Vth + (size_t)(b * NHEAD + h) * DK * SEQ;
        const int d = t >> 2, c0 = (t & 3) * 32;
        #pragma unroll
        for (int i = 0; i < 4; ++i) {
            half8 v = *(const half8*)&Vl[d * 136 + c0 + i * 8];
            *(half8*)(dst + (size_t)d * SEQ + l0 + c0 + i * 8) = v;
        }
    }
}

// ---------------------------------------------------------------------------
// Kernel 2: flash attention, fp16 MFMA, max-free softmax, 128 q-rows/block,
//   double-buffered K/V with TWO barriers per tile (writes happen in a
//   window where no wave can be reading either buffer — race-proof even if
//   the one-barrier hazard analysis is wrong), register prefetch, XCD swizzle.
// grid: 512 linear, block 256
// ---------------------------------------------------------------------------
__global__ __launch_bounds__(256) void attn_mfma_kernel(
    const _Float16* __restrict__ Qh, const _Float16* __restrict__ Kwh,
    const _Float16* __restrict__ Vth, _Float16* __restrict__ AOh)
{
    // buf0 = SM[0](K),SM[1](V); buf1 = SM[2](K),SM[3](V). Q staged via SM[2..3].
    __shared__ _Float16 SM[4][64][72];   // 36.9 KB

    const int bx = blockIdx.x;           // 0..511
    const int g8 = bx & 7;               // XCD (dispatch round-robin)
    const int s  = bx >> 3;              // 0..63
    const int bh = g8 * 4 + (s >> 4);    // XCD g owns bh 4g..4g+3 (K/V 2MB in L2)
    const int q0 = (s & 15) * 128;
    const int b = bh >> 3, h = bh & 7;

    const int t = threadIdx.x;
    const int w = t >> 6, lane = t & 63, ln = lane & 15, quad = lane >> 4;

    const _Float16* Qg = Qh + ((size_t)bh * SEQ + q0) * DK;
    const _Float16* Kg = Kwh + (size_t)bh * SEQ * DK;
    const _Float16* Vg = Vth + (size_t)bh * DK * SEQ;

    const int sr = t >> 2, sc = (t & 3) * 16;   // K/V staging: row 0..63, 16 cols
    const int qr = t >> 1, qc = (t & 1) * 32;   // Q staging: row 0..127, 32 cols

    // prologue: stage Q (into buf1 space) and K0,V0 (into buf0)
    {
        const _Float16* qp = Qg + (size_t)qr * DK + qc;
        half8 qv0 = *(const half8*)(qp);
        half8 qv1 = *(const half8*)(qp + 8);
        half8 qv2 = *(const half8*)(qp + 16);
        half8 qv3 = *(const half8*)(qp + 24);
        const _Float16* kp = Kg + (size_t)sr * DK + sc;
        const _Float16* vp = Vg + (size_t)sr * SEQ + sc;
        half8 kv0 = *(const half8*)(kp);
        half8 kv1 = *(const half8*)(kp + 8);
        half8 vv0 = *(const half8*)(vp);
        half8 vv1 = *(const half8*)(vp + 8);
        _Float16* qd = &SM[2 + (qr >> 6)][qr & 63][qc];
        *(half8*)(qd)      = qv0;
        *(half8*)(qd + 8)  = qv1;
        *(half8*)(qd + 16) = qv2;
        *(half8*)(qd + 24) = qv3;
        *(half8*)&SM[0][sr][sc]     = kv0;
        *(half8*)&SM[0][sr][sc + 8] = kv1;
        *(half8*)&SM[1][sr][sc]     = vv0;
        *(half8*)&SM[1][sr][sc + 8] = vv1;
    }
    __syncthreads();

    // extract Q fragments: wave w handles q rows w*32 .. w*32+31 (2 groups of 16)
    half8 qf[2][2];
    #pragma unroll
    for (int u = 0; u < 2; ++u) {
        const int row = w * 32 + u * 16 + ln;
        const _Float16* qsrc = &SM[2 + (row >> 6)][row & 63][0];
        qf[u][0] = *(const half8*)(qsrc + quad * 8);
        qf[u][1] = *(const half8*)(qsrc + 32 + quad * 8);
    }
    __syncthreads();   // protect buf1 (Q space) from kt=0 writes

    const f32x4 kZero = {0.f, 0.f, 0.f, 0.f};
    f32x4 o[2][4];         // o[u][nt][r]: q row u*16+quad*4+r, d col nt*16+ln
    #pragma unroll
    for (int u = 0; u < 2; ++u)
        #pragma unroll
        for (int nt = 0; nt < 4; ++nt) o[u][nt] = kZero;
    float l_acc[2] = {0.f, 0.f};   // per-lane partial denom, q row = w*32+u*16+ln

    for (int kt = 0; kt < SEQ / 64; ++kt) {
        const int cur = kt & 1;

        // prefetch next tile into registers (latency hidden by compute)
        half8 pk0, pk1, pv0, pv1;
        const bool more = (kt + 1 < SEQ / 64);
        if (more) {
            const _Float16* kp = Kg + (size_t)((kt + 1) * 64 + sr) * DK + sc;
            const _Float16* vp = Vg + (size_t)sr * SEQ + (kt + 1) * 64 + sc;
            pk0 = *(const half8*)(kp);
            pk1 = *(const half8*)(kp + 8);
            pv0 = *(const half8*)(vp);
            pv1 = *(const half8*)(vp + 8);
        }

        const _Float16 (*Ks)[72] = SM[2 * cur];
        const _Float16 (*Vs)[72] = SM[2 * cur + 1];

        #pragma unroll
        for (int g = 0; g < 2; ++g) {
            half8 ka0 = *(const half8*)&Ks[(2 * g + 0) * 16 + ln][quad * 8];
            half8 ka1 = *(const half8*)&Ks[(2 * g + 0) * 16 + ln][32 + quad * 8];
            half8 kb0 = *(const half8*)&Ks[(2 * g + 1) * 16 + ln][quad * 8];
            half8 kb1 = *(const half8*)&Ks[(2 * g + 1) * 16 + ln][32 + quad * 8];
            half8 vf[4];
            #pragma unroll
            for (int nt = 0; nt < 4; ++nt)
                vf[nt] = *(const half8*)&Vs[nt * 16 + ln][g * 32 + quad * 8];

            #pragma unroll
            for (int u = 0; u < 2; ++u) {
                f32x4 s0 = MFMA32(ka0, qf[u][0], kZero);
                f32x4 s1 = MFMA32(kb0, qf[u][0], kZero);
                s0 = MFMA32(ka1, qf[u][1], s0);
                s1 = MFMA32(kb1, qf[u][1], s1);

                half8 pf;
                float ps = 0.f;
                #pragma unroll
                for (int r = 0; r < 4; ++r) {
                    const float e0 = __expf(s0[r]);
                    const float e1 = __expf(s1[r]);
                    pf[r]     = (_Float16)e0;
                    pf[r + 4] = (_Float16)e1;
                    ps += e0 + e1;
                }
                l_acc[u] += ps;

                #pragma unroll
                for (int nt = 0; nt < 4; ++nt)
                    o[u][nt] = MFMA32(pf, vf[nt], o[u][nt]);
            }
        }

        // barrier: all waves done reading BOTH buffers before anyone writes
        __syncthreads();
        if (more) {
            _Float16* kd = &SM[2 * (cur ^ 1)][sr][sc];
            _Float16* vd = &SM[2 * (cur ^ 1) + 1][sr][sc];
            *(half8*)(kd)     = pk0;
            *(half8*)(kd + 8) = pk1;
            *(half8*)(vd)     = pv0;
            *(half8*)(vd + 8) = pv1;
        }
        // barrier: writes visible before next iteration's reads
        __syncthreads();
    }

    // reduce denominators across quads (lanes ln, 16+ln, 32+ln, 48+ln)
    #pragma unroll
    for (int u = 0; u < 2; ++u) {
        l_acc[u] += __shfl_xor(l_acc[u], 16);
        l_acc[u] += __shfl_xor(l_acc[u], 32);
    }

    // normalize + store AO (B, L, 512) fp16
    #pragma unroll
    for (int u = 0; u < 2; ++u)
        #pragma unroll
        for (int r = 0; r < 4; ++r) {
            const float lr  = __shfl(l_acc[u], quad * 4 + r, 16);
            const float inv = 1.0f / lr;
            const int lq = q0 + w * 32 + u * 16 + quad * 4 + r;
            const size_t base = ((size_t)b * SEQ + lq) * D_MODEL + h * DK;
            #pragma unroll
            for (int nt = 0; nt < 4; ++nt)
                AOh[base + nt * 16 + ln] = (_Float16)(o[u][nt][r] * inv);
        }
}

// ---------------------------------------------------------------------------
// Kernel 3: output projection, fp16 MFMA.  out = AOh @ Woh^T  (fp32 out)
// grid: (8, 64), block 256
// ---------------------------------------------------------------------------
__global__ __launch_bounds__(256) void out_mfma_kernel(
    const _Float16* __restrict__ AOh, const _Float16* __restrict__ Woh,
    float* __restrict__ out)
{
    __shared__ _Float16 As[128][72];
    __shared__ _Float16 Bs[64][72];

    const int t  = threadIdx.x;
    const int n0 = blockIdx.x * 64;
    const int m0 = blockIdx.y * 128;

    const int w = t >> 6, lane = t & 63, ln = lane & 15, quad = lane >> 4;
    const int ar = t >> 1, ac = (t & 1) * 32;
    const int br = t >> 2, bc = (t & 3) * 16;

    const _Float16* ag = AOh + (size_t)(m0 + ar) * 512 + ac;
    const _Float16* bg = Woh + (size_t)(n0 + br) * 512 + bc;

    const f32x4 kZero = {0.f, 0.f, 0.f, 0.f};
    f32x4 acc[2][4];
    #pragma unroll
    for (int i = 0; i < 2; ++i)
        #pragma unroll
        for (int j = 0; j < 4; ++j) acc[i][j] = kZero;

    for (int k0 = 0; k0 < 512; k0 += 64) {
        half8 av[4], bv[2];
        #pragma unroll
        for (int i = 0; i < 4; ++i) av[i] = *(const half8*)(ag + k0 + i * 8);
        #pragma unroll
        for (int i = 0; i < 2; ++i) bv[i] = *(const half8*)(bg + k0 + i * 8);
        __syncthreads();
        #pragma unroll
        for (int i = 0; i < 4; ++i) *(half8*)&As[ar][ac + i * 8] = av[i];
        #pragma unroll
        for (int i = 0; i < 2; ++i) *(half8*)&Bs[br][bc + i * 8] = bv[i];
        __syncthreads();

        #pragma unroll
        for (int ks = 0; ks < 2; ++ks) {
            half8 af[2], bf[4];
            #pragma unroll
            for (int mt = 0; mt < 2; ++mt)
                af[mt] = *(const half8*)&As[w * 32 + mt * 16 + ln][ks * 32 + quad * 8];
            #pragma unroll
            for (int nt = 0; nt < 4; ++nt)
                bf[nt] = *(const half8*)&Bs[nt * 16 + ln][ks * 32 + quad * 8];
            #pragma unroll
            for (int mt = 0; mt < 2; ++mt)
                #pragma unroll
                for (int nt = 0; nt < 4; ++nt)
                    acc[mt][nt] = MFMA32(af[mt], bf[nt], acc[mt][nt]);
        }
    }

    #pragma unroll
    for (int mt = 0; mt < 2; ++mt)
        #pragma unroll
        for (int nt = 0; nt < 4; ++nt)
            #pragma unroll
            for (int r = 0; r < 4; ++r) {
                const int gm = m0 + w * 32 + mt * 16 + quad * 4 + r;
                out[(size_t)gm * 512 + n0 + nt * 16 + ln] = acc[mt][nt][r];
            }
}

// ---------------------------------------------------------------------------
extern "C" void kernel_launch(void* const* d_in, const int* in_sizes, int n_in,
                              void* d_out, int out_size, void* d_ws, size_t ws_size,
                              hipStream_t stream)
{
    (void)in_sizes; (void)n_in; (void)out_size; (void)ws_size;
    const float* x  = (const float*)d_in[0];
    const float* Wq = (const float*)d_in[1];
    const float* Wk = (const float*)d_in[2];
    const float* Wv = (const float*)d_in[3];
    const float* Wo = (const float*)d_in[4];
    const float* wf = (const float*)d_in[5];
    const float* wp = (const float*)d_in[6];
    float* out = (float*)d_out;

    const size_t NX = (size_t)MTOT * D_MODEL;        // 4,194,304
    _Float16* Xh  = (_Float16*)d_ws;
    _Float16* Wh  = Xh + NX;                          // 4 x 262144
    _Float16* Qh  = Wh + 4 * 262144;
    _Float16* Kh  = Qh + NX;                          // pre-scaled K'
    _Float16* Vth = Kh + NX;                          // transposed+swizzled V
    _Float16* AOh = Vth + NX;
    float*    wtab = (float*)(AOh + NX);              // 8 x 2048 fp32

    cvt_kernel<<<5136, 256, 0, stream>>>(x, Wq, Wk, Wv, Wo, wf, wp, Xh, Wh, wtab);

    dim3 g1(24, 64);
    qkv_mfma_kernel<<<g1, 256, 0, stream>>>(Xh, Wh, wtab, Qh, Kh, Vth);

    attn_mfma_kernel<<<512, 256, 0, stream>>>(Qh, Kh, Vth, AOh);

    dim3 g3(8, 64);
    out_mfma_kernel<<<g3, 256, 0, stream>>>(AOh, Wh + 3 * 262144, out);
}

// Round 8
// 167.174 us; speedup vs baseline: 5.8181x; 1.0072x over previous
//
#include <hip/hip_runtime.h>
#include <math.h>

#define D_MODEL 512
#define NHEAD   8
#define DK      64
#define BATCH   4
#define SEQ     2048
#define MTOT    (BATCH*SEQ)
#define NXELEM  (MTOT*D_MODEL)          // 4,194,304
#define NWELEM  (4*D_MODEL*D_MODEL)     // 1,048,576

typedef _Float16 half8   __attribute__((ext_vector_type(8)));
typedef _Float16 half4_t __attribute__((ext_vector_type(4)));
typedef __fp16   fp16x2  __attribute__((ext_vector_type(2)));  // cvt_pkrtz return type
typedef float    f32x4   __attribute__((ext_vector_type(4)));

#define MFMA32(a,b,c) __builtin_amdgcn_mfma_f32_16x16x32_f16((a),(b),(c),0,0,0)

// wtab scale: dk^-0.5 * log2(e)  (log2e folded so attn uses raw v_exp_f32)
#define WSCALE 0.18033688011117130f

// ---------------------------------------------------------------------------
// Kernel 0: convert x + 4 weights to fp16, and build the wave table
//   wtab[h][pos] = 0.125 * log2e * cos(2*pi*f_h*pos + phase_h)
// grid: 5136 x 256 (last 16 blocks do wtab)
// ---------------------------------------------------------------------------
__global__ __launch_bounds__(256) void cvt_kernel(
    const float* __restrict__ x,
    const float* __restrict__ Wq, const float* __restrict__ Wk,
    const float* __restrict__ Wv, const float* __restrict__ Wo,
    const float* __restrict__ wf, const float* __restrict__ wp,
    _Float16* __restrict__ Xh, _Float16* __restrict__ Wh,
    float* __restrict__ wtab)
{
    const int tid = blockIdx.x * 256 + threadIdx.x;
    int idx = tid * 4;
    if (idx < NXELEM + NWELEM) {
        const float* src; _Float16* dst; int off;
        if (idx < NXELEM) { src = x; dst = Xh; off = idx; }
        else {
            int r = idx - NXELEM;
            int sel = r >> 18;                 // 512*512 = 2^18
            off = r & ((1 << 18) - 1);
            src = (sel == 0) ? Wq : (sel == 1) ? Wk : (sel == 2) ? Wv : Wo;
            dst = Wh + ((size_t)sel << 18);
        }
        float4 v = *(const float4*)(src + off);
        half4_t h;
        h[0] = (_Float16)v.x; h[1] = (_Float16)v.y;
        h[2] = (_Float16)v.z; h[3] = (_Float16)v.w;
        *(half4_t*)(dst + off) = h;
    } else {
        int widx = idx - (NXELEM + NWELEM);    // 0 .. 16380, 4-aligned
        const int h = widx >> 11;
        const int pos0 = widx & 2047;
        const float f  = 6.28318530717958647692f * wf[h];
        const float ph = wp[h];
        float4 o;
        o.x = WSCALE * cosf(fmaf(f, (float)(pos0 + 0), ph));
        o.y = WSCALE * cosf(fmaf(f, (float)(pos0 + 1), ph));
        o.z = WSCALE * cosf(fmaf(f, (float)(pos0 + 2), ph));
        o.w = WSCALE * cosf(fmaf(f, (float)(pos0 + 3), ph));
        *(float4*)(wtab + widx) = o;
    }
}

// ---------------------------------------------------------------------------
// Kernel 1: fused QKV projection, fp16 MFMA.  C = Xh @ Wcat^T
//   Q out: (B,H,L,64) fp16 raw.
//   K out: (B,H,L,64) fp16, PRE-MULTIPLIED by wtab[h][pos].
//   V out: transposed (B,H,64,L') fp16, pos swizzled per 32-key group so a
//          b128 read at [d][g*32+quad*8] is a K=32 PV B-fragment.
//   All epilogues use LDS repack -> vectorized b128 global stores.
// grid: (24, 64), block 256
// ---------------------------------------------------------------------------
__global__ __launch_bounds__(256) void qkv_mfma_kernel(
    const _Float16* __restrict__ Xh, const _Float16* __restrict__ Wh,
    const float* __restrict__ wtab,
    _Float16* __restrict__ Qh, _Float16* __restrict__ Kh,
    _Float16* __restrict__ Vth)
{
    __shared__ _Float16 As[128][72];   // [m][k], pad 8
    __shared__ _Float16 Bs[64][72];    // [n][k]

    const int t  = threadIdx.x;
    const int n0 = blockIdx.x * 64;        // 0..1535
    const int m0 = blockIdx.y * 128;
    const int which = n0 >> 9;             // 0=Q 1=K 2=V
    const int h = (n0 >> 6) & 7;
    const _Float16* Wbase = Wh + ((size_t)which << 18) + (size_t)(h * 64) * 512;

    const int w = t >> 6, lane = t & 63, ln = lane & 15, quad = lane >> 4;
    const int ar = t >> 1, ac = (t & 1) * 32;   // A staging: row, col
    const int br = t >> 2, bc = (t & 3) * 16;   // B staging

    const _Float16* ag = Xh + (size_t)(m0 + ar) * 512 + ac;
    const _Float16* bg = Wbase + (size_t)br * 512 + bc;

    const f32x4 kZero = {0.f, 0.f, 0.f, 0.f};
    f32x4 acc[2][4];
    #pragma unroll
    for (int i = 0; i < 2; ++i)
        #pragma unroll
        for (int j = 0; j < 4; ++j) acc[i][j] = kZero;

    for (int k0 = 0; k0 < 512; k0 += 64) {
        half8 av[4], bv[2];
        #pragma unroll
        for (int i = 0; i < 4; ++i) av[i] = *(const half8*)(ag + k0 + i * 8);
        #pragma unroll
        for (int i = 0; i < 2; ++i) bv[i] = *(const half8*)(bg + k0 + i * 8);
        __syncthreads();
        #pragma unroll
        for (int i = 0; i < 4; ++i) *(half8*)&As[ar][ac + i * 8] = av[i];
        #pragma unroll
        for (int i = 0; i < 2; ++i) *(half8*)&Bs[br][bc + i * 8] = bv[i];
        __syncthreads();

        #pragma unroll
        for (int ks = 0; ks < 2; ++ks) {
            half8 af[2], bf[4];
            #pragma unroll
            for (int mt = 0; mt < 2; ++mt)
                af[mt] = *(const half8*)&As[w * 32 + mt * 16 + ln][ks * 32 + quad * 8];
            #pragma unroll
            for (int nt = 0; nt < 4; ++nt)
                bf[nt] = *(const half8*)&Bs[nt * 16 + ln][ks * 32 + quad * 8];
            #pragma unroll
            for (int mt = 0; mt < 2; ++mt)
                #pragma unroll
                for (int nt = 0; nt < 4; ++nt)
                    acc[mt][nt] = MFMA32(af[mt], bf[nt], acc[mt][nt]);
        }
    }

    const int b  = m0 >> 11;
    const int l0 = m0 & 2047;

    if (which < 2) {
        // repack via LDS (row-major [lq][d]) -> coalesced half8 stores
        _Float16* dst = (which == 0 ? Qh : Kh) + (size_t)(b * NHEAD + h) * SEQ * DK;
        const float* wt = wtab + h * SEQ;
        __syncthreads();    // k-loop frag reads done before As reuse
        _Float16* Ql = &As[0][0];    // stride 72
        #pragma unroll
        for (int mt = 0; mt < 2; ++mt)
            #pragma unroll
            for (int r = 0; r < 4; ++r) {
                const int lr = w * 32 + mt * 16 + quad * 4 + r;   // 0..127
                const float wv = (which == 1) ? wt[l0 + lr] : 1.0f;
                #pragma unroll
                for (int nt = 0; nt < 4; ++nt)
                    Ql[lr * 72 + nt * 16 + ln] = (_Float16)(acc[mt][nt][r] * wv);
            }
        __syncthreads();
        #pragma unroll
        for (int rr = 0; rr < 4; ++rr) {
            const int row = rr * 32 + (t >> 3);
            half8 v = *(const half8*)&Ql[row * 72 + (t & 7) * 8];
            *(half8*)(dst + (size_t)(l0 + row) * DK + (t & 7) * 8) = v;
        }
    } else {
        // V: transpose + swizzle via LDS with b128 writes.
        // pos = w*32 + quad*8 + mt*4 + r  -> 8 contiguous halves per nt.
        __syncthreads();
        _Float16* Vl = &As[0][0];    // 64 x 136 halves = 17.4KB
        #pragma unroll
        for (int nt = 0; nt < 4; ++nt) {
            half8 hv;
            #pragma unroll
            for (int mt = 0; mt < 2; ++mt)
                #pragma unroll
                for (int r = 0; r < 4; ++r)
                    hv[mt * 4 + r] = (_Float16)acc[mt][nt][r];
            const int d = nt * 16 + ln;
            *(half8*)&Vl[d * 136 + w * 32 + quad * 8] = hv;
        }
        __syncthreads();
        _Float16* dst = Vth + (size_t)(b * NHEAD + h) * DK * SEQ;
        #pragma unroll
        for (int rr = 0; rr < 4; ++rr) {
            const int d = rr * 16 + (t >> 4);
            half8 v = *(const half8*)&Vl[d * 136 + (t & 15) * 8];
            *(half8*)(dst + (size_t)d * SEQ + l0 + (t & 15) * 8) = v;
        }
    }
}

// ---------------------------------------------------------------------------
// Kernel 2: flash attention, fp16 MFMA, max-free softmax (v_exp base-2),
//   128 q-rows/block, double-buffered K/V with TWO barriers per tile
//   (race-proof), register prefetch, XCD swizzle, pk-cvt P packing.
// grid: 512 linear, block 256
// ---------------------------------------------------------------------------
__global__ __launch_bounds__(256) void attn_mfma_kernel(
    const _Float16* __restrict__ Qh, const _Float16* __restrict__ Kwh,
    const _Float16* __restrict__ Vth, _Float16* __restrict__ AOh)
{
    // buf0 = SM[0](K),SM[1](V); buf1 = SM[2](K),SM[3](V). Q staged via SM[2..3].
    __shared__ _Float16 SM[4][64][72];   // 36.9 KB

    const int bx = blockIdx.x;           // 0..511
    const int g8 = bx & 7;               // XCD (dispatch round-robin)
    const int s  = bx >> 3;              // 0..63
    const int bh = g8 * 4 + (s >> 4);    // XCD g owns bh 4g..4g+3 (K/V 2MB in L2)
    const int q0 = (s & 15) * 128;
    const int b = bh >> 3, h = bh & 7;

    const int t = threadIdx.x;
    const int w = t >> 6, lane = t & 63, ln = lane & 15, quad = lane >> 4;

    const _Float16* Qg = Qh + ((size_t)bh * SEQ + q0) * DK;
    const _Float16* Kg = Kwh + (size_t)bh * SEQ * DK;
    const _Float16* Vg = Vth + (size_t)bh * DK * SEQ;

    const int sr = t >> 2, sc = (t & 3) * 16;   // K/V staging: row 0..63, 16 cols
    const int qr = t >> 1, qc = (t & 1) * 32;   // Q staging: row 0..127, 32 cols

    // prologue: stage Q (into buf1 space) and K0,V0 (into buf0)
    {
        const _Float16* qp = Qg + (size_t)qr * DK + qc;
        half8 qv0 = *(const half8*)(qp);
        half8 qv1 = *(const half8*)(qp + 8);
        half8 qv2 = *(const half8*)(qp + 16);
        half8 qv3 = *(const half8*)(qp + 24);
        const _Float16* kp = Kg + (size_t)sr * DK + sc;
        const _Float16* vp = Vg + (size_t)sr * SEQ + sc;
        half8 kv0 = *(const half8*)(kp);
        half8 kv1 = *(const half8*)(kp + 8);
        half8 vv0 = *(const half8*)(vp);
        half8 vv1 = *(const half8*)(vp + 8);
        _Float16* qd = &SM[2 + (qr >> 6)][qr & 63][qc];
        *(half8*)(qd)      = qv0;
        *(half8*)(qd + 8)  = qv1;
        *(half8*)(qd + 16) = qv2;
        *(half8*)(qd + 24) = qv3;
        *(half8*)&SM[0][sr][sc]     = kv0;
        *(half8*)&SM[0][sr][sc + 8] = kv1;
        *(half8*)&SM[1][sr][sc]     = vv0;
        *(half8*)&SM[1][sr][sc + 8] = vv1;
    }
    __syncthreads();

    // extract Q fragments: wave w handles q rows w*32 .. w*32+31 (2 groups of 16)
    half8 qf[2][2];
    #pragma unroll
    for (int u = 0; u < 2; ++u) {
        const int row = w * 32 + u * 16 + ln;
        const _Float16* qsrc = &SM[2 + (row >> 6)][row & 63][0];
        qf[u][0] = *(const half8*)(qsrc + quad * 8);
        qf[u][1] = *(const half8*)(qsrc + 32 + quad * 8);
    }
    __syncthreads();   // protect buf1 (Q space) from kt=0 writes

    const f32x4 kZero = {0.f, 0.f, 0.f, 0.f};
    f32x4 o[2][4];         // o[u][nt][r]: q row u*16+quad*4+r, d col nt*16+ln
    #pragma unroll
    for (int u = 0; u < 2; ++u)
        #pragma unroll
        for (int nt = 0; nt < 4; ++nt) o[u][nt] = kZero;
    float l_acc[2] = {0.f, 0.f};   // per-lane partial denom, q row = w*32+u*16+ln

    for (int kt = 0; kt < SEQ / 64; ++kt) {
        const int cur = kt & 1;

        // prefetch next tile into registers (latency hidden by compute)
        half8 pk0, pk1, pv0, pv1;
        const bool more = (kt + 1 < SEQ / 64);
        if (more) {
            const _Float16* kp = Kg + (size_t)((kt + 1) * 64 + sr) * DK + sc;
            const _Float16* vp = Vg + (size_t)sr * SEQ + (kt + 1) * 64 + sc;
            pk0 = *(const half8*)(kp);
            pk1 = *(const half8*)(kp + 8);
            pv0 = *(const half8*)(vp);
            pv1 = *(const half8*)(vp + 8);
        }

        const _Float16 (*Ks)[72] = SM[2 * cur];
        const _Float16 (*Vs)[72] = SM[2 * cur + 1];

        #pragma unroll
        for (int g = 0; g < 2; ++g) {
            half8 ka0 = *(const half8*)&Ks[(2 * g + 0) * 16 + ln][quad * 8];
            half8 ka1 = *(const half8*)&Ks[(2 * g + 0) * 16 + ln][32 + quad * 8];
            half8 kb0 = *(const half8*)&Ks[(2 * g + 1) * 16 + ln][quad * 8];
            half8 kb1 = *(const half8*)&Ks[(2 * g + 1) * 16 + ln][32 + quad * 8];
            half8 vf[4];
            #pragma unroll
            for (int nt = 0; nt < 4; ++nt)
                vf[nt] = *(const half8*)&Vs[nt * 16 + ln][g * 32 + quad * 8];

            #pragma unroll
            for (int u = 0; u < 2; ++u) {
                f32x4 s0 = MFMA32(ka0, qf[u][0], kZero);
                f32x4 s1 = MFMA32(kb0, qf[u][0], kZero);
                s0 = MFMA32(ka1, qf[u][1], s0);
                s1 = MFMA32(kb1, qf[u][1], s1);

                // p = 2^s (log2e pre-folded into K'); pack via v_cvt_pkrtz
                const float e00 = __builtin_amdgcn_exp2f(s0[0]);
                const float e01 = __builtin_amdgcn_exp2f(s0[1]);
                const float e02 = __builtin_amdgcn_exp2f(s0[2]);
                const float e03 = __builtin_amdgcn_exp2f(s0[3]);
                const float e10 = __builtin_amdgcn_exp2f(s1[0]);
                const float e11 = __builtin_amdgcn_exp2f(s1[1]);
                const float e12 = __builtin_amdgcn_exp2f(s1[2]);
                const float e13 = __builtin_amdgcn_exp2f(s1[3]);
                union { half8 v; fp16x2 h2[4]; } pu;
                pu.h2[0] = __builtin_amdgcn_cvt_pkrtz(e00, e01);
                pu.h2[1] = __builtin_amdgcn_cvt_pkrtz(e02, e03);
                pu.h2[2] = __builtin_amdgcn_cvt_pkrtz(e10, e11);
                pu.h2[3] = __builtin_amdgcn_cvt_pkrtz(e12, e13);
                l_acc[u] += ((e00 + e01) + (e02 + e03)) + ((e10 + e11) + (e12 + e13));

                #pragma unroll
                for (int nt = 0; nt < 4; ++nt)
                    o[u][nt] = MFMA32(pu.v, vf[nt], o[u][nt]);
            }
        }

        // barrier: all waves done reading BOTH buffers before anyone writes
        __syncthreads();
        if (more) {
            _Float16* kd = &SM[2 * (cur ^ 1)][sr][sc];
            _Float16* vd = &SM[2 * (cur ^ 1) + 1][sr][sc];
            *(half8*)(kd)     = pk0;
            *(half8*)(kd + 8) = pk1;
            *(half8*)(vd)     = pv0;
            *(half8*)(vd + 8) = pv1;
        }
        // barrier: writes visible before next iteration's reads
        __syncthreads();
    }

    // reduce denominators across quads (lanes ln, 16+ln, 32+ln, 48+ln)
    #pragma unroll
    for (int u = 0; u < 2; ++u) {
        l_acc[u] += __shfl_xor(l_acc[u], 16);
        l_acc[u] += __shfl_xor(l_acc[u], 32);
    }

    // normalize + store AO (B, L, 512) fp16
    #pragma unroll
    for (int u = 0; u < 2; ++u)
        #pragma unroll
        for (int r = 0; r < 4; ++r) {
            const float lr  = __shfl(l_acc[u], quad * 4 + r, 16);
            const float inv = 1.0f / lr;
            const int lq = q0 + w * 32 + u * 16 + quad * 4 + r;
            const size_t base = ((size_t)b * SEQ + lq) * D_MODEL + h * DK;
            #pragma unroll
            for (int nt = 0; nt < 4; ++nt)
                AOh[base + nt * 16 + ln] = (_Float16)(o[u][nt][r] * inv);
        }
}

// ---------------------------------------------------------------------------
// Kernel 3: output projection, fp16 MFMA.  out = AOh @ Woh^T  (fp32 out)
//   Two-pass LDS repack epilogue -> float4 stores.
// grid: (8, 64), block 256
// ---------------------------------------------------------------------------
__global__ __launch_bounds__(256) void out_mfma_kernel(
    const _Float16* __restrict__ AOh, const _Float16* __restrict__ Woh,
    float* __restrict__ out)
{
    __shared__ _Float16 As[128][72];
    __shared__ _Float16 Bs[64][72];

    const int t  = threadIdx.x;
    const int n0 = blockIdx.x * 64;
    const int m0 = blockIdx.y * 128;

    const int w = t >> 6, lane = t & 63, ln = lane & 15, quad = lane >> 4;
    const int ar = t >> 1, ac = (t & 1) * 32;
    const int br = t >> 2, bc = (t & 3) * 16;

    const _Float16* ag = AOh + (size_t)(m0 + ar) * 512 + ac;
    const _Float16* bg = Woh + (size_t)(n0 + br) * 512 + bc;

    const f32x4 kZero = {0.f, 0.f, 0.f, 0.f};
    f32x4 acc[2][4];
    #pragma unroll
    for (int i = 0; i < 2; ++i)
        #pragma unroll
        for (int j = 0; j < 4; ++j) acc[i][j] = kZero;

    for (int k0 = 0; k0 < 512; k0 += 64) {
        half8 av[4], bv[2];
        #pragma unroll
        for (int i = 0; i < 4; ++i) av[i] = *(const half8*)(ag + k0 + i * 8);
        #pragma unroll
        for (int i = 0; i < 2; ++i) bv[i] = *(const half8*)(bg + k0 + i * 8);
        __syncthreads();
        #pragma unroll
        for (int i = 0; i < 4; ++i) *(half8*)&As[ar][ac + i * 8] = av[i];
        #pragma unroll
        for (int i = 0; i < 2; ++i) *(half8*)&Bs[br][bc + i * 8] = bv[i];
        __syncthreads();

        #pragma unroll
        for (int ks = 0; ks < 2; ++ks) {
            half8 af[2], bf[4];
            #pragma unroll
            for (int mt = 0; mt < 2; ++mt)
                af[mt] = *(const half8*)&As[w * 32 + mt * 16 + ln][ks * 32 + quad * 8];
            #pragma unroll
            for (int nt = 0; nt < 4; ++nt)
                bf[nt] = *(const half8*)&Bs[nt * 16 + ln][ks * 32 + quad * 8];
            #pragma unroll
            for (int mt = 0; mt < 2; ++mt)
                #pragma unroll
                for (int nt = 0; nt < 4; ++nt)
                    acc[mt][nt] = MFMA32(af[mt], bf[nt], acc[mt][nt]);
        }
    }

    // two-pass repack: rows [0,64) then [64,128), float buffer aliases As
    float* Os = (float*)&As[0][0];     // [64][66] floats = 16.9KB <= 18.4KB
    #pragma unroll
    for (int pass = 0; pass < 2; ++pass) {
        __syncthreads();
        if ((w >> 1) == pass) {
            const int rbase = (w & 1) * 32;
            #pragma unroll
            for (int mt = 0; mt < 2; ++mt)
                #pragma unroll
                for (int r = 0; r < 4; ++r) {
                    const int row = rbase + mt * 16 + quad * 4 + r;
                    #pragma unroll
                    for (int nt = 0; nt < 4; ++nt)
                        Os[row * 66 + nt * 16 + ln] = acc[mt][nt][r];
                }
        }
        __syncthreads();
        #pragma unroll
        for (int rr = 0; rr < 4; ++rr) {
            const int row = rr * 16 + (t >> 4);
            float4 v = *(const float4*)&Os[row * 66 + (t & 15) * 4];
            *(float4*)(out + (size_t)(m0 + pass * 64 + row) * 512 + n0 + (t & 15) * 4) = v;
        }
    }
}

// ---------------------------------------------------------------------------
extern "C" void kernel_launch(void* const* d_in, const int* in_sizes, int n_in,
                              void* d_out, int out_size, void* d_ws, size_t ws_size,
                              hipStream_t stream)
{
    (void)in_sizes; (void)n_in; (void)out_size; (void)ws_size;
    const float* x  = (const float*)d_in[0];
    const float* Wq = (const float*)d_in[1];
    const float* Wk = (const float*)d_in[2];
    const float* Wv = (const float*)d_in[3];
    const float* Wo = (const float*)d_in[4];
    const float* wf = (const float*)d_in[5];
    const float* wp = (const float*)d_in[6];
    float* out = (float*)d_out;

    const size_t NX = (size_t)MTOT * D_MODEL;        // 4,194,304
    _Float16* Xh  = (_Float16*)d_ws;
    _Float16* Wh  = Xh + NX;                          // 4 x 262144
    _Float16* Qh  = Wh + 4 * 262144;
    _Float16* Kh  = Qh + NX;                          // pre-scaled K'
    _Float16* Vth = Kh + NX;                          // transposed+swizzled V
    _Float16* AOh = Vth + NX;
    float*    wtab = (float*)(AOh + NX);              // 8 x 2048 fp32

    cvt_kernel<<<5136, 256, 0, stream>>>(x, Wq, Wk, Wv, Wo, wf, wp, Xh, Wh, wtab);

    dim3 g1(24, 64);
    qkv_mfma_kernel<<<g1, 256, 0, stream>>>(Xh, Wh, wtab, Qh, Kh, Vth);

    attn_mfma_kernel<<<512, 256, 0, stream>>>(Qh, Kh, Vth, AOh);

    dim3 g3(8, 64);
    out_mfma_kernel<<<g3, 256, 0, stream>>>(AOh, Wh + 3 * 262144, out);
}

// Round 9
// 155.727 us; speedup vs baseline: 6.2458x; 1.0735x over previous
//
#include <hip/hip_runtime.h>
#include <math.h>

#define D_MODEL 512
#define NHEAD   8
#define DK      64
#define BATCH   4
#define SEQ     2048
#define MTOT    (BATCH*SEQ)
#define NXELEM  (MTOT*D_MODEL)          // 4,194,304
#define NWELEM  (4*D_MODEL*D_MODEL)     // 1,048,576

typedef _Float16 half8   __attribute__((ext_vector_type(8)));
typedef _Float16 half4_t __attribute__((ext_vector_type(4)));
typedef __fp16   fp16x2  __attribute__((ext_vector_type(2)));  // cvt_pkrtz return type
typedef float    f32x4   __attribute__((ext_vector_type(4)));

#define MFMA32(a,b,c) __builtin_amdgcn_mfma_f32_16x16x32_f16((a),(b),(c),0,0,0)

// wtab scale: dk^-0.5 * log2(e)  (log2e folded so attn uses raw v_exp_f32)
#define WSCALE 0.18033688011117130f

// ---------------------------------------------------------------------------
// Kernel 0: convert x + 4 weights to fp16, and build the wave table
//   wtab[h][pos] = 0.125 * log2e * cos(2*pi*f_h*pos + phase_h)
// grid: 5136 x 256 (last 16 blocks do wtab)
// ---------------------------------------------------------------------------
__global__ __launch_bounds__(256) void cvt_kernel(
    const float* __restrict__ x,
    const float* __restrict__ Wq, const float* __restrict__ Wk,
    const float* __restrict__ Wv, const float* __restrict__ Wo,
    const float* __restrict__ wf, const float* __restrict__ wp,
    _Float16* __restrict__ Xh, _Float16* __restrict__ Wh,
    float* __restrict__ wtab)
{
    const int tid = blockIdx.x * 256 + threadIdx.x;
    int idx = tid * 4;
    if (idx < NXELEM + NWELEM) {
        const float* src; _Float16* dst; int off;
        if (idx < NXELEM) { src = x; dst = Xh; off = idx; }
        else {
            int r = idx - NXELEM;
            int sel = r >> 18;                 // 512*512 = 2^18
            off = r & ((1 << 18) - 1);
            src = (sel == 0) ? Wq : (sel == 1) ? Wk : (sel == 2) ? Wv : Wo;
            dst = Wh + ((size_t)sel << 18);
        }
        float4 v = *(const float4*)(src + off);
        half4_t h;
        h[0] = (_Float16)v.x; h[1] = (_Float16)v.y;
        h[2] = (_Float16)v.z; h[3] = (_Float16)v.w;
        *(half4_t*)(dst + off) = h;
    } else {
        int widx = idx - (NXELEM + NWELEM);    // 0 .. 16380, 4-aligned
        const int h = widx >> 11;
        const int pos0 = widx & 2047;
        const float f  = 6.28318530717958647692f * wf[h];
        const float ph = wp[h];
        float4 o;
        o.x = WSCALE * cosf(fmaf(f, (float)(pos0 + 0), ph));
        o.y = WSCALE * cosf(fmaf(f, (float)(pos0 + 1), ph));
        o.z = WSCALE * cosf(fmaf(f, (float)(pos0 + 2), ph));
        o.w = WSCALE * cosf(fmaf(f, (float)(pos0 + 3), ph));
        *(float4*)(wtab + widx) = o;
    }
}

// ---------------------------------------------------------------------------
// Kernel 1: fused QKV projection, fp16 MFMA.  One block computes Q,K,V for
//   one (h, 128-row m-tile) — Xh tile is read ONCE per h (A-traffic 200->67MB).
//   Q out: (B,H,L,64) fp16 raw.
//   K out: (B,H,L,64) fp16, PRE-MULTIPLIED by wtab[h][pos].
//   V out: transposed (B,H,64,L') fp16, pos swizzled per 32-key group so a
//          b128 read at [d][g*32+quad*8] is a K=32 PV B-fragment.
// grid: (8, 64), block 256
// ---------------------------------------------------------------------------
__global__ __launch_bounds__(256) void qkv_mfma_kernel(
    const _Float16* __restrict__ Xh, const _Float16* __restrict__ Wh,
    const float* __restrict__ wtab,
    _Float16* __restrict__ Qh, _Float16* __restrict__ Kh,
    _Float16* __restrict__ Vth)
{
    __shared__ _Float16 As[128][72];   // [m][k], pad 8          18.4 KB
    __shared__ _Float16 Bs[192][72];   // [which*64 + n][k]      27.6 KB

    const int t  = threadIdx.x;
    const int h  = blockIdx.x;
    const int m0 = blockIdx.y * 128;

    const int w = t >> 6, lane = t & 63, ln = lane & 15, quad = lane >> 4;
    const int ar = t >> 1, ac = (t & 1) * 32;   // A staging: row 0..127
    const int br = t >> 2, bc = (t & 3) * 16;   // B staging: row 0..63 per which

    const _Float16* ag  = Xh + (size_t)(m0 + ar) * 512 + ac;
    const _Float16* bg0 = Wh + (size_t)(h * 64 + br) * 512 + bc;   // Q weights
    const _Float16* bg1 = bg0 + (1 << 18);                          // K
    const _Float16* bg2 = bg0 + (2 << 18);                          // V

    const f32x4 kZero = {0.f, 0.f, 0.f, 0.f};
    f32x4 acc[3][2][4];
    #pragma unroll
    for (int c = 0; c < 3; ++c)
        #pragma unroll
        for (int i = 0; i < 2; ++i)
            #pragma unroll
            for (int j = 0; j < 4; ++j) acc[c][i][j] = kZero;

    for (int k0 = 0; k0 < 512; k0 += 64) {
        half8 av[4], bv[6];
        #pragma unroll
        for (int i = 0; i < 4; ++i) av[i] = *(const half8*)(ag + k0 + i * 8);
        bv[0] = *(const half8*)(bg0 + k0);
        bv[1] = *(const half8*)(bg0 + k0 + 8);
        bv[2] = *(const half8*)(bg1 + k0);
        bv[3] = *(const half8*)(bg1 + k0 + 8);
        bv[4] = *(const half8*)(bg2 + k0);
        bv[5] = *(const half8*)(bg2 + k0 + 8);
        __syncthreads();
        #pragma unroll
        for (int i = 0; i < 4; ++i) *(half8*)&As[ar][ac + i * 8] = av[i];
        #pragma unroll
        for (int c = 0; c < 3; ++c) {
            *(half8*)&Bs[c * 64 + br][bc]     = bv[2 * c];
            *(half8*)&Bs[c * 64 + br][bc + 8] = bv[2 * c + 1];
        }
        __syncthreads();

        #pragma unroll
        for (int ks = 0; ks < 2; ++ks) {
            half8 af[2];
            #pragma unroll
            for (int mt = 0; mt < 2; ++mt)
                af[mt] = *(const half8*)&As[w * 32 + mt * 16 + ln][ks * 32 + quad * 8];
            #pragma unroll
            for (int c = 0; c < 3; ++c) {
                half8 bf[4];
                #pragma unroll
                for (int nt = 0; nt < 4; ++nt)
                    bf[nt] = *(const half8*)&Bs[c * 64 + nt * 16 + ln][ks * 32 + quad * 8];
                #pragma unroll
                for (int mt = 0; mt < 2; ++mt)
                    #pragma unroll
                    for (int nt = 0; nt < 4; ++nt)
                        acc[c][mt][nt] = MFMA32(af[mt], bf[nt], acc[c][mt][nt]);
            }
        }
    }

    const int b  = m0 >> 11;
    const int l0 = m0 & 2047;
    const float* wt = wtab + h * SEQ;

    // Q then K: repack via As-LDS -> coalesced half8 stores
    #pragma unroll
    for (int which = 0; which < 2; ++which) {
        _Float16* dst = (which == 0 ? Qh : Kh) + (size_t)(b * NHEAD + h) * SEQ * DK;
        __syncthreads();
        _Float16* Ql = &As[0][0];    // stride 72
        #pragma unroll
        for (int mt = 0; mt < 2; ++mt)
            #pragma unroll
            for (int r = 0; r < 4; ++r) {
                const int lr = w * 32 + mt * 16 + quad * 4 + r;   // 0..127
                const float wv = (which == 1) ? wt[l0 + lr] : 1.0f;
                #pragma unroll
                for (int nt = 0; nt < 4; ++nt)
                    Ql[lr * 72 + nt * 16 + ln] = (_Float16)(acc[which][mt][nt][r] * wv);
            }
        __syncthreads();
        #pragma unroll
        for (int rr = 0; rr < 4; ++rr) {
            const int row = rr * 32 + (t >> 3);
            half8 v = *(const half8*)&Ql[row * 72 + (t & 7) * 8];
            *(half8*)(dst + (size_t)(l0 + row) * DK + (t & 7) * 8) = v;
        }
    }

    // V: transpose + swizzle via LDS with b128 writes.
    __syncthreads();
    _Float16* Vl = &As[0][0];    // 64 x 136 halves = 17.4KB
    #pragma unroll
    for (int nt = 0; nt < 4; ++nt) {
        half8 hv;
        #pragma unroll
        for (int mt = 0; mt < 2; ++mt)
            #pragma unroll
            for (int r = 0; r < 4; ++r)
                hv[mt * 4 + r] = (_Float16)acc[2][mt][nt][r];
        const int d = nt * 16 + ln;
        *(half8*)&Vl[d * 136 + w * 32 + quad * 8] = hv;
    }
    __syncthreads();
    _Float16* dst = Vth + (size_t)(b * NHEAD + h) * DK * SEQ;
    #pragma unroll
    for (int rr = 0; rr < 4; ++rr) {
        const int d = rr * 16 + (t >> 4);
        half8 v = *(const half8*)&Vl[d * 136 + (t & 15) * 8];
        *(half8*)(dst + (size_t)d * SEQ + l0 + (t & 15) * 8) = v;
    }
}

// ---------------------------------------------------------------------------
// Kernel 2: flash attention, fp16 MFMA, max-free softmax, IN-BLOCK SPLIT-K:
//   512 threads / 8 waves; waves 0-3 process keys 0..1023, waves 4-7 keys
//   1024..2047, each half with its own double-buffered K/V LDS region.
//   Max-free softmax => o,l are pure sums => halves combine exactly in-block.
//   Two barriers per tile (race-proof), register prefetch, XCD swizzle.
// grid: 512 linear, block 512
// ---------------------------------------------------------------------------
__global__ __launch_bounds__(512, 4) void attn_mfma_kernel(
    const _Float16* __restrict__ Qh, const _Float16* __restrict__ Kwh,
    const _Float16* __restrict__ Vth, _Float16* __restrict__ AOh)
{
    // SM[half][buf][row][col]; per half: buf0={0:K,1:V}, buf1={2:K,3:V}.
    // Q is staged through SM[1][2..3] (group 1's buf1, dead until end of kt=0).
    __shared__ _Float16 SM[2][4][64][72];   // 73.7 KB

    const int bx = blockIdx.x;           // 0..511
    const int g8 = bx & 7;               // XCD (dispatch round-robin)
    const int s  = bx >> 3;              // 0..63
    const int bh = g8 * 4 + (s >> 4);    // XCD g owns bh 4g..4g+3
    const int q0 = (s & 15) * 128;
    const int b = bh >> 3, h = bh & 7;

    const int t = threadIdx.x;           // 0..511
    const int w = t >> 6;                // 0..7
    const int wg = w & 3;                // q-row group (shared by both halves)
    const int half = w >> 2;             // key half
    const int lane = t & 63, ln = lane & 15, quad = lane >> 4;

    const _Float16* Qg = Qh + ((size_t)bh * SEQ + q0) * DK;
    const _Float16* Kg = Kwh + (size_t)bh * SEQ * DK;
    const _Float16* Vg = Vth + (size_t)bh * DK * SEQ;
    const int kbase = half * 1024;

    const int tl = t & 255;
    const int sr = tl >> 2, sc = (tl & 3) * 16;   // per-half K/V staging
    const int qr = t >> 2, qc = (t & 3) * 16;     // Q staging (all 512 threads)

    // prologue: stage Q (SM[1][2..3]) and this half's K0,V0 (SM[half][0..1])
    {
        const _Float16* qp = Qg + (size_t)qr * DK + qc;
        half8 qv0 = *(const half8*)(qp);
        half8 qv1 = *(const half8*)(qp + 8);
        const _Float16* kp = Kg + (size_t)(kbase + sr) * DK + sc;
        const _Float16* vp = Vg + (size_t)sr * SEQ + kbase + sc;
        half8 kv0 = *(const half8*)(kp);
        half8 kv1 = *(const half8*)(kp + 8);
        half8 vv0 = *(const half8*)(vp);
        half8 vv1 = *(const half8*)(vp + 8);
        _Float16* qd = &SM[1][2 + (qr >> 6)][qr & 63][qc];
        *(half8*)(qd)     = qv0;
        *(half8*)(qd + 8) = qv1;
        *(half8*)&SM[half][0][sr][sc]     = kv0;
        *(half8*)&SM[half][0][sr][sc + 8] = kv1;
        *(half8*)&SM[half][1][sr][sc]     = vv0;
        *(half8*)&SM[half][1][sr][sc + 8] = vv1;
    }
    __syncthreads();

    // extract Q fragments (same for both halves; rows by wg)
    half8 qf[2][2];
    #pragma unroll
    for (int u = 0; u < 2; ++u) {
        const int row = wg * 32 + u * 16 + ln;
        const _Float16* qsrc = &SM[1][2 + (row >> 6)][row & 63][0];
        qf[u][0] = *(const half8*)(qsrc + quad * 8);
        qf[u][1] = *(const half8*)(qsrc + 32 + quad * 8);
    }
    // no barrier needed here: first write to SM[1][2..3] happens only after
    // the kt=0 compute + in-loop barrier, which all waves must reach.

    const f32x4 kZero = {0.f, 0.f, 0.f, 0.f};
    f32x4 o[2][4];         // o[u][nt][r]: q row wg*32+u*16+quad*4+r, d col nt*16+ln
    #pragma unroll
    for (int u = 0; u < 2; ++u)
        #pragma unroll
        for (int nt = 0; nt < 4; ++nt) o[u][nt] = kZero;
    float l_acc[2] = {0.f, 0.f};

    for (int kt = 0; kt < 16; ++kt) {    // 16 tiles of 64 keys per half
        const int cur = kt & 1;

        half8 pk0, pk1, pv0, pv1;
        const bool more = (kt + 1 < 16);
        if (more) {
            const _Float16* kp = Kg + (size_t)(kbase + (kt + 1) * 64 + sr) * DK + sc;
            const _Float16* vp = Vg + (size_t)sr * SEQ + kbase + (kt + 1) * 64 + sc;
            pk0 = *(const half8*)(kp);
            pk1 = *(const half8*)(kp + 8);
            pv0 = *(const half8*)(vp);
            pv1 = *(const half8*)(vp + 8);
        }

        const _Float16 (*Ks)[72] = SM[half][2 * cur];
        const _Float16 (*Vs)[72] = SM[half][2 * cur + 1];

        #pragma unroll
        for (int g = 0; g < 2; ++g) {
            half8 ka0 = *(const half8*)&Ks[(2 * g + 0) * 16 + ln][quad * 8];
            half8 ka1 = *(const half8*)&Ks[(2 * g + 0) * 16 + ln][32 + quad * 8];
            half8 kb0 = *(const half8*)&Ks[(2 * g + 1) * 16 + ln][quad * 8];
            half8 kb1 = *(const half8*)&Ks[(2 * g + 1) * 16 + ln][32 + quad * 8];
            half8 vf[4];
            #pragma unroll
            for (int nt = 0; nt < 4; ++nt)
                vf[nt] = *(const half8*)&Vs[nt * 16 + ln][g * 32 + quad * 8];

            #pragma unroll
            for (int u = 0; u < 2; ++u) {
                f32x4 s0 = MFMA32(ka0, qf[u][0], kZero);
                f32x4 s1 = MFMA32(kb0, qf[u][0], kZero);
                s0 = MFMA32(ka1, qf[u][1], s0);
                s1 = MFMA32(kb1, qf[u][1], s1);

                const float e00 = __builtin_amdgcn_exp2f(s0[0]);
                const float e01 = __builtin_amdgcn_exp2f(s0[1]);
                const float e02 = __builtin_amdgcn_exp2f(s0[2]);
                const float e03 = __builtin_amdgcn_exp2f(s0[3]);
                const float e10 = __builtin_amdgcn_exp2f(s1[0]);
                const float e11 = __builtin_amdgcn_exp2f(s1[1]);
                const float e12 = __builtin_amdgcn_exp2f(s1[2]);
                const float e13 = __builtin_amdgcn_exp2f(s1[3]);
                union { half8 v; fp16x2 h2[4]; } pu;
                pu.h2[0] = __builtin_amdgcn_cvt_pkrtz(e00, e01);
                pu.h2[1] = __builtin_amdgcn_cvt_pkrtz(e02, e03);
                pu.h2[2] = __builtin_amdgcn_cvt_pkrtz(e10, e11);
                pu.h2[3] = __builtin_amdgcn_cvt_pkrtz(e12, e13);
                l_acc[u] += ((e00 + e01) + (e02 + e03)) + ((e10 + e11) + (e12 + e13));

                #pragma unroll
                for (int nt = 0; nt < 4; ++nt)
                    o[u][nt] = MFMA32(pu.v, vf[nt], o[u][nt]);
            }
        }

        __syncthreads();                 // all reads of both buffers done
        if (more) {
            _Float16* kd = &SM[half][2 * (cur ^ 1)][sr][sc];
            _Float16* vd = &SM[half][2 * (cur ^ 1) + 1][sr][sc];
            *(half8*)(kd)     = pk0;
            *(half8*)(kd + 8) = pk1;
            *(half8*)(vd)     = pv0;
            *(half8*)(vd + 8) = pv1;
        }
        __syncthreads();                 // writes visible before next reads
    }

    // ---- combine the two key-halves (exact: o,l are pure sums) ----
    // conflict-free layout: slot-major, stride 257 floats
    float* OP = (float*)&SM[0][0][0][0];      // 34 slots x 257 = 34.9 KB
    const int idx = wg * 64 + lane;           // 0..255
    if (half == 1) {
        #pragma unroll
        for (int u = 0; u < 2; ++u)
            #pragma unroll
            for (int nt = 0; nt < 4; ++nt)
                #pragma unroll
                for (int r = 0; r < 4; ++r)
                    OP[((u * 4 + nt) * 4 + r) * 257 + idx] = o[u][nt][r];
        OP[32 * 257 + idx] = l_acc[0];
        OP[33 * 257 + idx] = l_acc[1];
    }
    __syncthreads();
    if (half == 0) {
        #pragma unroll
        for (int u = 0; u < 2; ++u)
            #pragma unroll
            for (int nt = 0; nt < 4; ++nt)
                #pragma unroll
                for (int r = 0; r < 4; ++r)
                    o[u][nt][r] += OP[((u * 4 + nt) * 4 + r) * 257 + idx];
        l_acc[0] += OP[32 * 257 + idx];
        l_acc[1] += OP[33 * 257 + idx];

        // reduce denominators across quads
        #pragma unroll
        for (int u = 0; u < 2; ++u) {
            l_acc[u] += __shfl_xor(l_acc[u], 16);
            l_acc[u] += __shfl_xor(l_acc[u], 32);
        }

        // normalize + store AO (B, L, 512) fp16
        #pragma unroll
        for (int u = 0; u < 2; ++u)
            #pragma unroll
            for (int r = 0; r < 4; ++r) {
                const float lr  = __shfl(l_acc[u], quad * 4 + r, 16);
                const float inv = 1.0f / lr;
                const int lq = q0 + wg * 32 + u * 16 + quad * 4 + r;
                const size_t base = ((size_t)b * SEQ + lq) * D_MODEL + h * DK;
                #pragma unroll
                for (int nt = 0; nt < 4; ++nt)
                    AOh[base + nt * 16 + ln] = (_Float16)(o[u][nt][r] * inv);
            }
    }
}

// ---------------------------------------------------------------------------
// Kernel 3: output projection, fp16 MFMA.  out = AOh @ Woh^T  (fp32 out)
//   Two-pass LDS repack epilogue -> float4 stores.
// grid: (8, 64), block 256
// ---------------------------------------------------------------------------
__global__ __launch_bounds__(256) void out_mfma_kernel(
    const _Float16* __restrict__ AOh, const _Float16* __restrict__ Woh,
    float* __restrict__ out)
{
    __shared__ _Float16 As[128][72];
    __shared__ _Float16 Bs[64][72];

    const int t  = threadIdx.x;
    const int n0 = blockIdx.x * 64;
    const int m0 = blockIdx.y * 128;

    const int w = t >> 6, lane = t & 63, ln = lane & 15, quad = lane >> 4;
    const int ar = t >> 1, ac = (t & 1) * 32;
    const int br = t >> 2, bc = (t & 3) * 16;

    const _Float16* ag = AOh + (size_t)(m0 + ar) * 512 + ac;
    const _Float16* bg = Woh + (size_t)(n0 + br) * 512 + bc;

    const f32x4 kZero = {0.f, 0.f, 0.f, 0.f};
    f32x4 acc[2][4];
    #pragma unroll
    for (int i = 0; i < 2; ++i)
        #pragma unroll
        for (int j = 0; j < 4; ++j) acc[i][j] = kZero;

    for (int k0 = 0; k0 < 512; k0 += 64) {
        half8 av[4], bv[2];
        #pragma unroll
        for (int i = 0; i < 4; ++i) av[i] = *(const half8*)(ag + k0 + i * 8);
        #pragma unroll
        for (int i = 0; i < 2; ++i) bv[i] = *(const half8*)(bg + k0 + i * 8);
        __syncthreads();
        #pragma unroll
        for (int i = 0; i < 4; ++i) *(half8*)&As[ar][ac + i * 8] = av[i];
        #pragma unroll
        for (int i = 0; i < 2; ++i) *(half8*)&Bs[br][bc + i * 8] = bv[i];
        __syncthreads();

        #pragma unroll
        for (int ks = 0; ks < 2; ++ks) {
            half8 af[2], bf[4];
            #pragma unroll
            for (int mt = 0; mt < 2; ++mt)
                af[mt] = *(const half8*)&As[w * 32 + mt * 16 + ln][ks * 32 + quad * 8];
            #pragma unroll
            for (int nt = 0; nt < 4; ++nt)
                bf[nt] = *(const half8*)&Bs[nt * 16 + ln][ks * 32 + quad * 8];
            #pragma unroll
            for (int mt = 0; mt < 2; ++mt)
                #pragma unroll
                for (int nt = 0; nt < 4; ++nt)
                    acc[mt][nt] = MFMA32(af[mt], bf[nt], acc[mt][nt]);
        }
    }

    // two-pass repack: rows [0,64) then [64,128), float buffer aliases As
    float* Os = (float*)&As[0][0];     // [64][66] floats = 16.9KB
    #pragma unroll
    for (int pass = 0; pass < 2; ++pass) {
        __syncthreads();
        if ((w >> 1) == pass) {
            const int rbase = (w & 1) * 32;
            #pragma unroll
            for (int mt = 0; mt < 2; ++mt)
                #pragma unroll
                for (int r = 0; r < 4; ++r) {
                    const int row = rbase + mt * 16 + quad * 4 + r;
                    #pragma unroll
                    for (int nt = 0; nt < 4; ++nt)
                        Os[row * 66 + nt * 16 + ln] = acc[mt][nt][r];
                }
        }
        __syncthreads();
        #pragma unroll
        for (int rr = 0; rr < 4; ++rr) {
            const int row = rr * 16 + (t >> 4);
            float4 v = *(const float4*)&Os[row * 66 + (t & 15) * 4];
            *(float4*)(out + (size_t)(m0 + pass * 64 + row) * 512 + n0 + (t & 15) * 4) = v;
        }
    }
}

// ---------------------------------------------------------------------------
extern "C" void kernel_launch(void* const* d_in, const int* in_sizes, int n_in,
                              void* d_out, int out_size, void* d_ws, size_t ws_size,
                              hipStream_t stream)
{
    (void)in_sizes; (void)n_in; (void)out_size; (void)ws_size;
    const float* x  = (const float*)d_in[0];
    const float* Wq = (const float*)d_in[1];
    const float* Wk = (const float*)d_in[2];
    const float* Wv = (const float*)d_in[3];
    const float* Wo = (const float*)d_in[4];
    const float* wf = (const float*)d_in[5];
    const float* wp = (const float*)d_in[6];
    float* out = (float*)d_out;

    const size_t NX = (size_t)MTOT * D_MODEL;        // 4,194,304
    _Float16* Xh  = (_Float16*)d_ws;
    _Float16* Wh  = Xh + NX;                          // 4 x 262144
    _Float16* Qh  = Wh + 4 * 262144;
    _Float16* Kh  = Qh + NX;                          // pre-scaled K'
    _Float16* Vth = Kh + NX;                          // transposed+swizzled V
    _Float16* AOh = Vth + NX;
    float*    wtab = (float*)(AOh + NX);              // 8 x 2048 fp32

    cvt_kernel<<<5136, 256, 0, stream>>>(x, Wq, Wk, Wv, Wo, wf, wp, Xh, Wh, wtab);

    dim3 g1(8, 64);
    qkv_mfma_kernel<<<g1, 256, 0, stream>>>(Xh, Wh, wtab, Qh, Kh, Vth);

    attn_mfma_kernel<<<512, 512, 0, stream>>>(Qh, Kh, Vth, AOh);

    dim3 g3(8, 64);
    out_mfma_kernel<<<g3, 256, 0, stream>>>(AOh, Wh + 3 * 262144, out);
}